// Round 6
// baseline (499.179 us; speedup 1.0000x reference)
//
#include <hip/hip_runtime.h>
#include <stdint.h>

// LinearAttention (gated delta rule), S=2048, HID=2048, H=16, DK=64, DV=128, conv K=4.
// r16: chunk_b was single-CU LDS-pipe-bound (89.6us = 6720cyc/chunk; ~4200 cyc of
// ds-op serialization across 4 waves sharing one CU's LDS pipe; only 32 CUs active).
// Changes: (1) 64 blocks (h x v-quarter, 32 v each) -> per-CU LDS traffic ~halves,
// 2x CUs; (2) dlocT [v][t] layout (chunk_a writes transposed, coalesced) -> Dl gather
// 16 scalar u16 reads -> 2 b64 reads; (3) B2 = raw s_barrier + lgkmcnt(0) only (T4):
// prefetch issued after B1 stays in flight across B2, drains at next B1 (~free).
// Math bit-identical to r15 (same MFMA chains / rounding sites).

#define SEQ 2048
#define HIDDEN 2048
#define NH 16
#define DKv 64
#define DVv 128
#define KEY_DIM 1024
#define VAL_DIM 2048
#define CONV_DIM 4096

typedef __bf16 bf16;
typedef unsigned short u16;
typedef __attribute__((ext_vector_type(8))) __bf16 bf16x8;
typedef __attribute__((ext_vector_type(4))) __bf16 bf16x4;
typedef __attribute__((ext_vector_type(4))) float f32x4;

#define AS1 __attribute__((address_space(1)))
#define AS3 __attribute__((address_space(3)))
#define GLDS16(src, dst) __builtin_amdgcn_global_load_lds((AS1 const void*)(src), (AS3 void*)(dst), 16, 0, 0)

__device__ __forceinline__ float b2f(u16 u) {
  union { unsigned int i; float f; } c; c.i = ((unsigned int)u) << 16; return c.f;
}
__device__ __forceinline__ float sigmoidf_(float x) { return 1.0f / (1.0f + __expf(-x)); }

// ---------------------------------------------------------------- dtype detector
__global__ void detect_dtype(const u16* __restrict__ p, unsigned* __restrict__ flag) {
  int lane = threadIdx.x;  // 64 threads
  int cnt = 0;
  for (int w = lane; w < 2048; w += 64) {
    unsigned e = (p[2 * w] >> 7) & 0xFF;
    if (e < 64) cnt++;
  }
  cnt += __shfl_xor(cnt, 1);  cnt += __shfl_xor(cnt, 2);  cnt += __shfl_xor(cnt, 4);
  cnt += __shfl_xor(cnt, 8);  cnt += __shfl_xor(cnt, 16); cnt += __shfl_xor(cnt, 32);
  if (lane == 0) *flag = (cnt > 64) ? 1u : 0u;   // 1 = inputs are f32
}

// ---------------------------------------------------------------- f32 -> bf16 convert
__global__ __launch_bounds__(256)
void cvt_bf16(const void* __restrict__ src, bf16* __restrict__ dst, long n,
              const unsigned* __restrict__ flagp) {
  long i = ((long)blockIdx.x * 256 + threadIdx.x) * 8;
  if (i >= n) return;
  if (*flagp) {
    const f32x4* s = (const f32x4*)((const float*)src + i);
    f32x4 a = s[0], b = s[1];
    bf16x8 o;
#pragma unroll
    for (int j = 0; j < 4; ++j) { o[j] = (bf16)a[j]; o[4 + j] = (bf16)b[j]; }
    *(bf16x8*)(dst + i) = o;
  } else {
    *(bf16x8*)(dst + i) = *(const bf16x8*)((const bf16*)src + i);
  }
}

// ---------------------------------------------------------------- GEMM (NT) standalone
template<bool F32OUT>
__global__ __launch_bounds__(256, 2)
void gemm_nt(const void* __restrict__ Araw, const void* __restrict__ Braw,
             void* __restrict__ Cv, int N, int K,
             const unsigned* __restrict__ flagp, int useA, int useB) {
  __shared__ __align__(16) bf16 As[128 * 32];
  __shared__ __align__(16) bf16 Bs[128 * 32];
  const bool f32g = (*flagp != 0);
  const bool fA = useA && f32g;
  const bool fB = useB && f32g;
  const int tid  = threadIdx.x;
  const int lane = tid & 63;
  const int wv   = tid >> 6;
  const int wm   = (wv & 1) << 6;
  const int wn   = (wv >> 1) << 6;
  const long bm  = (long)blockIdx.y * 128;
  const long bn  = (long)blockIdx.x * 128;

  f32x4 acc[4][4] = {};

  for (int k0 = 0; k0 < K; k0 += 32) {
#pragma unroll
    for (int it = 0; it < 2; ++it) {
      int e   = (it * 256 + tid) * 8;
      int row = e >> 5;
      int col = e & 31;
      long offA = (bm + row) * (long)K + (k0 + col);
      long offB = (bn + row) * (long)K + (k0 + col);
      if (fA) {
        const float* g = (const float*)Araw + offA;
        f32x4 u0 = *(const f32x4*)g, u1 = *(const f32x4*)(g + 4);
        bf16x8 bv;
#pragma unroll
        for (int j = 0; j < 4; ++j) { bv[j] = (bf16)u0[j]; bv[4 + j] = (bf16)u1[j]; }
        *(bf16x8*)&As[e] = bv;
      } else {
        const bf16* g = (const bf16*)Araw + offA;
        GLDS16(g, &As[e]);
      }
      if (fB) {
        const float* g = (const float*)Braw + offB;
        f32x4 u0 = *(const f32x4*)g, u1 = *(const f32x4*)(g + 4);
        bf16x8 bv;
#pragma unroll
        for (int j = 0; j < 4; ++j) { bv[j] = (bf16)u0[j]; bv[4 + j] = (bf16)u1[j]; }
        *(bf16x8*)&Bs[e] = bv;
      } else {
        const bf16* g = (const bf16*)Braw + offB;
        GLDS16(g, &Bs[e]);
      }
    }
    __syncthreads();

    const bf16x8* As8 = (const bf16x8*)As;
    const bf16x8* Bs8 = (const bf16x8*)Bs;
    const int r = lane & 15, q = lane >> 4;
    bf16x8 af[4], bfr[4];
#pragma unroll
    for (int i = 0; i < 4; ++i) af[i]  = As8[(wm + i * 16 + r) * 4 + q];
#pragma unroll
    for (int j = 0; j < 4; ++j) bfr[j] = Bs8[(wn + j * 16 + r) * 4 + q];
#pragma unroll
    for (int i = 0; i < 4; ++i)
#pragma unroll
      for (int j = 0; j < 4; ++j)
        acc[i][j] = __builtin_amdgcn_mfma_f32_16x16x32_bf16(af[i], bfr[j], acc[i][j], 0, 0, 0);
    __syncthreads();
  }

  const int r = lane & 15, q = lane >> 4;
#pragma unroll
  for (int i = 0; i < 4; ++i)
#pragma unroll
    for (int j = 0; j < 4; ++j) {
      long row = bm + wm + i * 16 + q * 4;
      long col = bn + wn + j * 16 + r;
#pragma unroll
      for (int rr = 0; rr < 4; ++rr) {
        if constexpr (F32OUT) ((float*)Cv)[(row + rr) * N + col] = acc[i][j][rr];
        else                  ((bf16*)Cv)[(row + rr) * N + col] = (bf16)acc[i][j][rr];
      }
    }
}

// ---------------------------------------------------------------- GEMM body (bf16-only, fused)
__device__ void gemm_body_bf16(char* smemc, const bf16* __restrict__ A,
                               const bf16* __restrict__ B, bf16* __restrict__ C,
                               int N, int K, int bx, int by, int tid) {
  bf16* As = (bf16*)smemc;             // 8 KiB
  bf16* Bs = (bf16*)(smemc + 8192);    // 8 KiB
  const int lane = tid & 63;
  const int wv = tid >> 6, wm = (wv & 1) << 6, wn = (wv >> 1) << 6;
  const long bm = (long)by * 128, bn = (long)bx * 128;
  f32x4 acc[4][4] = {};
  for (int k0 = 0; k0 < K; k0 += 32) {
#pragma unroll
    for (int it = 0; it < 2; ++it) {
      int e = (it * 256 + tid) * 8;
      int row = e >> 5, col = e & 31;
      const bf16* gA = A + (bm + row) * (long)K + k0 + col;
      const bf16* gB = B + (bn + row) * (long)K + k0 + col;
      GLDS16(gA, &As[e]);
      GLDS16(gB, &Bs[e]);
    }
    __syncthreads();
    const bf16x8* As8 = (const bf16x8*)As;
    const bf16x8* Bs8 = (const bf16x8*)Bs;
    const int r = lane & 15, q = lane >> 4;
    bf16x8 af[4], bfr[4];
#pragma unroll
    for (int i = 0; i < 4; ++i) af[i]  = As8[(wm + i * 16 + r) * 4 + q];
#pragma unroll
    for (int j = 0; j < 4; ++j) bfr[j] = Bs8[(wn + j * 16 + r) * 4 + q];
#pragma unroll
    for (int i = 0; i < 4; ++i)
#pragma unroll
      for (int j = 0; j < 4; ++j)
        acc[i][j] = __builtin_amdgcn_mfma_f32_16x16x32_bf16(af[i], bfr[j], acc[i][j], 0, 0, 0);
    __syncthreads();
  }
  const int r = lane & 15, q = lane >> 4;
#pragma unroll
  for (int i = 0; i < 4; ++i)
#pragma unroll
    for (int j = 0; j < 4; ++j) {
      long row = bm + wm + i * 16 + q * 4;
      long col = bn + wn + j * 16 + r;
#pragma unroll
      for (int rr = 0; rr < 4; ++rr)
        C[(row + rr) * (long)N + col] = (bf16)acc[i][j][rr];
    }
}

// ---------------------------------------------------------------- a/b proj -> exp(g), g, beta
__global__ __launch_bounds__(256)
void proj_ab(const void* __restrict__ hsr, const void* __restrict__ War,
             const void* __restrict__ Wbr, const void* __restrict__ A_logr,
             const void* __restrict__ dtbr,
             float* __restrict__ eg, float* __restrict__ bet,
             float* __restrict__ gb,
             const unsigned* __restrict__ flagp) {
  const bool f32g = (*flagp != 0);
  const int t  = threadIdx.x;
  const int sl = t >> 5;
  const int o  = t & 31;
  const int h  = o & 15;
  const long s = (long)blockIdx.x * 8 + sl;
  float a0 = 0.f, a1 = 0.f, a2 = 0.f, a3 = 0.f;
  if (f32g) {
    const f32x4* x4 = (const f32x4*)((const float*)hsr + s * HIDDEN);
    const f32x4* w4 = (const f32x4*)((const float*)((o < 16) ? War : Wbr) + (long)h * HIDDEN);
#pragma unroll 8
    for (int k4 = 0; k4 < 512; ++k4) {
      f32x4 xv = x4[k4], wv = w4[k4];
      a0 = fmaf(xv[0], wv[0], a0);
      a1 = fmaf(xv[1], wv[1], a1);
      a2 = fmaf(xv[2], wv[2], a2);
      a3 = fmaf(xv[3], wv[3], a3);
    }
  } else {
    const bf16x8* x8 = (const bf16x8*)((const bf16*)hsr + s * HIDDEN);
    const bf16x8* w8 = (const bf16x8*)((const bf16*)((o < 16) ? War : Wbr) + (long)h * HIDDEN);
#pragma unroll 8
    for (int k8 = 0; k8 < 256; ++k8) {
      bf16x8 xv = x8[k8], wv = w8[k8];
      a0 += (float)xv[0] * (float)wv[0] + (float)xv[4] * (float)wv[4];
      a1 += (float)xv[1] * (float)wv[1] + (float)xv[5] * (float)wv[5];
      a2 += (float)xv[2] * (float)wv[2] + (float)xv[6] * (float)wv[6];
      a3 += (float)xv[3] * (float)wv[3] + (float)xv[7] * (float)wv[7];
    }
  }
  const float a = (a0 + a1) + (a2 + a3);
  if (o < 16) {
    float alog = f32g ? ((const float*)A_logr)[h] : b2f(((const u16*)A_logr)[h]);
    float dtb  = f32g ? ((const float*)dtbr)[h]   : b2f(((const u16*)dtbr)[h]);
    float xx = a + dtb;
    float sp = fmaxf(xx, 0.f) + log1pf(__expf(-fabsf(xx)));   // stable softplus
    float gg = -__expf(alog) * sp;                             // log-decay
    if (gb) gb[s * NH + h] = gg;
    eg[s * NH + h] = __expf(gg);
  } else {
    bet[s * NH + h] = sigmoidf_(a);
  }
}

// ---------------------------------------------------------------- conv + SiLU + l2norm
__global__ __launch_bounds__(256)
void conv_norm(const bf16* __restrict__ mixed, const void* __restrict__ convwr,
               bf16* __restrict__ qbuf, bf16* __restrict__ kbuf, bf16* __restrict__ vbuf,
               const unsigned* __restrict__ flagp) {
  const bool f32g = (*flagp != 0);
  const int s = blockIdx.x;
  const int c = blockIdx.y * 256 + threadIdx.x;
  float w0, w1, w2, w3;
  if (f32g) {
    const float* wp = (const float*)convwr + (long)c * 4;
    w0 = wp[0]; w1 = wp[1]; w2 = wp[2]; w3 = wp[3];
  } else {
    const u16* wp = (const u16*)convwr + (long)c * 4;
    w0 = b2f(wp[0]); w1 = b2f(wp[1]); w2 = b2f(wp[2]); w3 = b2f(wp[3]);
  }
  float acc = w3 * (float)mixed[(long)s * CONV_DIM + c];
  if (s >= 1) acc += w2 * (float)mixed[(long)(s - 1) * CONV_DIM + c];
  if (s >= 2) acc += w1 * (float)mixed[(long)(s - 2) * CONV_DIM + c];
  if (s >= 3) acc += w0 * (float)mixed[(long)(s - 3) * CONV_DIM + c];
  float y = acc * sigmoidf_(acc);  // SiLU
  if (c < 2 * KEY_DIM) {
    float ss = y * y;
    ss += __shfl_xor(ss, 1);  ss += __shfl_xor(ss, 2);  ss += __shfl_xor(ss, 4);
    ss += __shfl_xor(ss, 8);  ss += __shfl_xor(ss, 16); ss += __shfl_xor(ss, 32);
    float scale = rsqrtf(ss + 1e-6f);
    if (c < KEY_DIM) scale *= 0.125f;
    y *= scale;
  }
  if (c < KEY_DIM)            qbuf[(long)s * KEY_DIM + c] = (bf16)y;
  else if (c < 2 * KEY_DIM)   kbuf[(long)s * KEY_DIM + (c - KEY_DIM)] = (bf16)y;
  else                        vbuf[(long)s * VAL_DIM + (c - 2 * KEY_DIM)] = (bf16)y;
}

// ---------------------------------------------------------------- DPP 16-lane sum (fallback scan)
template<int CTRL>
__device__ __forceinline__ float dpp_add(float x) {
  int y = __builtin_amdgcn_update_dpp(0, __float_as_int(x), CTRL, 0xF, 0xF, true);
  return x + __int_as_float(y);
}
__device__ __forceinline__ float dpp_sum16(float x) {
  x = dpp_add<0xB1>(x);   // quad_perm xor1
  x = dpp_add<0x4E>(x);   // quad_perm xor2
  x = dpp_add<0x141>(x);  // row_half_mirror (xor4)
  x = dpp_add<0x140>(x);  // row_mirror (xor8)
  return x;
}

// ---------------------------------------------------------------- fused per-step scan (FALLBACK path only)
__global__ __launch_bounds__(256, 2)
void fused_scan(const bf16* __restrict__ qbuf, const bf16* __restrict__ kbuf,
                const bf16* __restrict__ vbuf, const float* __restrict__ eg,
                const float* __restrict__ bet, bf16* __restrict__ core,
                const bf16* __restrict__ hsb, const bf16* __restrict__ wzb,
                bf16* __restrict__ zbuf, const void* __restrict__ woutr,
                bf16* __restrict__ woutb, const unsigned* __restrict__ flagp,
                int nScan, int nGemm) {
  __shared__ __align__(16) char smem[16384];
  const int t = threadIdx.x;
  const int b = blockIdx.x;

  if (b < nScan) {
    const int h  = b >> 3;
    const int vg = (b & 7) * 16;
    const int g  = t >> 4;
    const int L  = t & 15;
    bf16*  kqs = (bf16*)smem;               // [2][2048] elems
    bf16*  vts = (bf16*)(smem + 8192);      // [2][256] elems
    float* ets = (float*)(smem + 9216);     // [2][16]
    float* bts = (float*)(smem + 9344);     // [2][16]

#define STAGE(buf, s0)                                                          \
    {                                                                           \
      int byte = t * 16;                                                        \
      const bf16* src;                                                          \
      if (byte < 2048) {                                                        \
        int row = byte >> 7, el = (byte & 127) >> 1;                            \
        src = kbuf + (long)((s0) + row) * KEY_DIM + h * DKv + el;               \
      } else {                                                                  \
        int b2 = byte - 2048;                                                   \
        int row = b2 >> 7, el = (b2 & 127) >> 1;                                \
        src = qbuf + (long)((s0) + row) * KEY_DIM + h * DKv + el;               \
      }                                                                         \
      GLDS16(src, smem + (buf) * 4096 + byte);                                  \
      if (t < 32) {                                                             \
        int row = t >> 1, el = (t & 1) * 8;                                     \
        const bf16* vsrc = vbuf + (long)((s0) + row) * VAL_DIM + h * DVv + vg + el; \
        GLDS16(vsrc, smem + 8192 + (buf) * 512 + t * 16);                       \
      }                                                                         \
    }

    float er = 0.f, br = 0.f;
    if (t < 16)      er = eg[(long)t * NH + h];
    else if (t < 32) br = bet[(long)(t - 16) * NH + h];
    STAGE(0, 0);
    if (t < 16)      ets[t] = er;
    else if (t < 32) bts[t - 16] = br;
    __syncthreads();

    float S0 = 0.f, S1 = 0.f, S2 = 0.f, S3 = 0.f;
    for (int tile = 0; tile < 128; ++tile) {
      const int buf = tile & 1, nb = buf ^ 1;
      if (tile < 127) {
        STAGE(nb, (tile + 1) * 16);
        if (t < 16)      er = eg[(long)((tile + 1) * 16 + t) * NH + h];
        else if (t < 32) br = bet[(long)((tile + 1) * 16 + (t - 16)) * NH + h];
      }
      const bf16*  ktb = kqs + buf * 2048;
      const bf16*  qtb = ktb + 1024;
      const bf16*  vtb = vts + buf * 256;
      const float* etb = ets + buf * 16;
      const float* btb = bts + buf * 16;
      const long sbase = (long)tile * 16;

      bf16x4 kR[2], qR[2];
      float  vR[2], eR[2], bR[2];
      kR[0] = *(const bf16x4*)(ktb + 0 * 64 + L * 4);
      qR[0] = *(const bf16x4*)(qtb + 0 * 64 + L * 4);
      vR[0] = (float)vtb[0 * 16 + g];  eR[0] = etb[0];  bR[0] = btb[0];
      kR[1] = *(const bf16x4*)(ktb + 1 * 64 + L * 4);
      qR[1] = *(const bf16x4*)(qtb + 1 * 64 + L * 4);
      vR[1] = (float)vtb[1 * 16 + g];  eR[1] = etb[1];  bR[1] = btb[1];
#pragma unroll
      for (int s = 0; s < 16; ++s) {
        const int sl = s & 1;
        bf16x4 kk = kR[sl], qq = qR[sl];
        float vv = vR[sl], ee = eR[sl], bb = bR[sl];
        if (s < 14) {
          const int s2 = s + 2;
          kR[sl] = *(const bf16x4*)(ktb + s2 * 64 + L * 4);
          qR[sl] = *(const bf16x4*)(qtb + s2 * 64 + L * 4);
          vR[sl] = (float)vtb[s2 * 16 + g];
          eR[sl] = etb[s2];  bR[sl] = btb[s2];
        }
        float ebt = ee * bb, vbt = vv * bb;
        float k0 = (float)kk[0], k1 = (float)kk[1], k2 = (float)kk[2], k3 = (float)kk[3];
        float D0 = S0 * ee, D1 = S1 * ee, D2 = S2 * ee, D3 = S3 * ee;
        float p = (k0 * S0 + k1 * S1) + (k2 * S2 + k3 * S3);
        p = dpp_sum16(p);
        float delta = vbt - ebt * p;
        S0 = fmaf(k0, delta, D0); S1 = fmaf(k1, delta, D1);
        S2 = fmaf(k2, delta, D2); S3 = fmaf(k3, delta, D3);
        float q0 = (float)qq[0], q1 = (float)qq[1], q2 = (float)qq[2], q3 = (float)qq[3];
        float o = (q0 * S0 + q1 * S1) + (q2 * S2 + q3 * S3);
        o = dpp_sum16(o);
        if (L == 0) core[(sbase + s) * VAL_DIM + h * DVv + vg + g] = (bf16)o;
      }
      if (tile < 127) {
        if (t < 16)      ets[nb * 16 + t] = er;
        else if (t < 32) bts[nb * 16 + (t - 16)] = br;
      }
      __syncthreads();
    }
#undef STAGE
  } else if (b < nScan + nGemm) {
    int gb = b - nScan;
    gemm_body_bf16(smem, hsb, wzb, zbuf, VAL_DIM, HIDDEN, gb & 15, gb >> 4, t);
  } else {
    long i = ((long)(b - nScan - nGemm) * 256 + t) * 8;
    if (i < (long)HIDDEN * VAL_DIM) {
      if (*flagp) {
        const f32x4* s = (const f32x4*)((const float*)woutr + i);
        f32x4 a = s[0], c = s[1];
        bf16x8 o;
#pragma unroll
        for (int j = 0; j < 4; ++j) { o[j] = (bf16)a[j]; o[4 + j] = (bf16)c[j]; }
        *(bf16x8*)(woutb + i) = o;
      } else {
        *(bf16x8*)(woutb + i) = *(const bf16x8*)((const bf16*)woutr + i);
      }
    }
  }
}

// ================================================================ CHUNKED DELTA RULE
// chunk length 64, 32 chunks, 16 heads. Per chunk-head (c,h):
//   cum_t = prefix-sum of g; d_t = e^{cum_t}
//   A[t][i] = beta_t e^{cum_t-cum_i} (k_t.k_i), strictly lower
//   [Dloc | W] = (I+A)^{-1} [diag(beta)V | diag(beta*d)K]
//   delta = Dloc - W S0;  S' = e^{cumC} S0 + K'^T delta, K'[i]=e^{cumC-cum_i}k_i
//   O = diag(d) Q S0 + (Minc o Q K^T) delta
// dlocT[(c,h)][v][t] bf16 (d_out+8M); negW hi/lo [t][k] bf16 (ws+24M,+28M);
// dTg[(c,h)][v][t] bf16 (ws+0); o1g[(c,h)][v][t] bf16 pre-scaled by d_t (ws+8M).

// ---------------------------------------------------------------- phase A (+ fused zgemm + woutcvt)
__global__ __launch_bounds__(256, 2)
void chunk_a(const bf16* __restrict__ kbuf, const bf16* __restrict__ vbuf,
             const float* __restrict__ gbuf, const float* __restrict__ betp,
             bf16* __restrict__ dlocT, bf16* __restrict__ whig, bf16* __restrict__ wlog,
             const bf16* __restrict__ hsb, const bf16* __restrict__ wzb,
             bf16* __restrict__ zbuf, const void* __restrict__ woutr,
             bf16* __restrict__ woutb, const unsigned* __restrict__ flagp) {
  __shared__ __align__(16) char smem[25600];
  const int t = threadIdx.x;
  const int b = blockIdx.x;
  if (b < 512) {
    const int c = b >> 4, h = b & 15;
    bf16*  Ks   = (bf16*)smem;                 // [64][64] 8192 B
    float* At   = (float*)(smem + 8192);       // [64][64] 16384 B, At[i][t] = A[t][i]
    float* cumS = (float*)(smem + 24576);      // 64
    float* bS   = (float*)(smem + 24832);      // 64
    float* dS   = (float*)(smem + 25088);      // 64
    // stage K chunk -> LDS (linear)
#pragma unroll
    for (int it = 0; it < 2; ++it) {
      int byte = (it * 256 + t) * 16;
      int row = byte >> 7, col = (byte & 127) >> 1;
      const bf16* src = kbuf + (long)(c * 64 + row) * KEY_DIM + h * DKv + col;
      GLDS16(src, smem + byte);
    }
    if (t < 64) {  // wave 0: within-chunk prefix sum of log-decay
      float cc = gbuf[(long)(c * 64 + t) * NH + h];
#pragma unroll
      for (int d = 1; d < 64; d <<= 1) { float y = __shfl_up(cc, d); if (t >= d) cc += y; }
      cumS[t] = cc;
      dS[t] = __expf(cc);
      bS[t] = betp[(long)(c * 64 + t) * NH + h];
    }
    {  // zero At (upper+diag must read as 0 in the quad-vectorized substitution)
      f32x4 z = {0.f, 0.f, 0.f, 0.f};
#pragma unroll
      for (int i = 0; i < 4; ++i) ((f32x4*)At)[t * 4 + i] = z;
    }
    __syncthreads();
    // G = K K^T via MFMA; masked+scaled, stored transposed into At
    {
      const int lane = t & 63, wv = t >> 6;
      const int r = lane & 15, q = lane >> 4;
      const bf16x8* Ks8 = (const bf16x8*)Ks;
#pragma unroll
      for (int n = 0; n < 4; ++n) {
        f32x4 acc = {0.f, 0.f, 0.f, 0.f};
#pragma unroll
        for (int kk = 0; kk < 2; ++kk) {
          bf16x8 af  = Ks8[(wv * 16 + r) * 8 + kk * 4 + q];
          bf16x8 bfv = Ks8[(n  * 16 + r) * 8 + kk * 4 + q];
          acc = __builtin_amdgcn_mfma_f32_16x16x32_bf16(af, bfv, acc, 0, 0, 0);
        }
        const int i = n * 16 + r;
#pragma unroll
        for (int rr = 0; rr < 4; ++rr) {
          const int tr = wv * 16 + q * 4 + rr;
          if (i < tr)
            At[i * 64 + tr] = bS[tr] * __expf(cumS[tr] - cumS[i]) * acc[rr];
        }
      }
    }
    __syncthreads();
    // column-parallel forward substitution: x = (I+A)^{-1} r, one column per thread
    if (t < 192) {
      float x[64];
      const long ch = (long)(c * 16 + h);
      if (t < 128) {
#pragma unroll
        for (int s = 0; s < 64; ++s)
          x[s] = bS[s] * (float)vbuf[(long)(c * 64 + s) * VAL_DIM + h * DVv + t];
      } else {
        const int k = t - 128;
#pragma unroll
        for (int s = 0; s < 64; ++s)
          x[s] = bS[s] * dS[s] * (float)Ks[s * 64 + k];
      }
#pragma unroll
      for (int s = 0; s < 64; ++s) {
        const float val = x[s];
        const f32x4* row4 = (const f32x4*)(At + s * 64);
#pragma unroll
        for (int qd = (s >> 2); qd < 16; ++qd) {
          f32x4 a4 = row4[qd];
          x[qd * 4 + 0] = fmaf(-a4[0], val, x[qd * 4 + 0]);
          x[qd * 4 + 1] = fmaf(-a4[1], val, x[qd * 4 + 1]);
          x[qd * 4 + 2] = fmaf(-a4[2], val, x[qd * 4 + 2]);
          x[qd * 4 + 3] = fmaf(-a4[3], val, x[qd * 4 + 3]);
        }
      }
      if (t < 128) {          // Dloc column v=t -> dlocT[v][s] contiguous (bf16x4)
        bf16* dp = dlocT + ch * 8192 + (long)t * 64;
#pragma unroll
        for (int s4 = 0; s4 < 16; ++s4) {
          bf16x4 o;
          o[0] = (bf16)x[s4 * 4 + 0]; o[1] = (bf16)x[s4 * 4 + 1];
          o[2] = (bf16)x[s4 * 4 + 2]; o[3] = (bf16)x[s4 * 4 + 3];
          *(bf16x4*)(dp + s4 * 4) = o;
        }
      } else {                // W column k -> negW hi/lo [t][k] (coalesced per-s across wave)
        const int k = t - 128;
        const long wb = ch * 4096;
#pragma unroll
        for (int s = 0; s < 64; ++s) {
          float v = -x[s];
          bf16 hh = (bf16)v;
          whig[wb + s * 64 + k] = hh;
          wlog[wb + s * 64 + k] = (bf16)(v - (float)hh);
        }
      }
    }
  } else if (b < 768) {
    int gb = b - 512;
    gemm_body_bf16(smem, hsb, wzb, zbuf, VAL_DIM, HIDDEN, gb & 15, gb >> 4, t);
  } else {
    long i = ((long)(b - 768) * 256 + t) * 8;
    if (i < (long)HIDDEN * VAL_DIM) {
      if (*flagp) {
        const f32x4* s = (const f32x4*)((const float*)woutr + i);
        f32x4 a = s[0], cc = s[1];
        bf16x8 o;
#pragma unroll
        for (int j = 0; j < 4; ++j) { o[j] = (bf16)a[j]; o[4 + j] = (bf16)cc[j]; }
        *(bf16x8*)(woutb + i) = o;
      } else {
        *(bf16x8*)(woutb + i) = *(const bf16x8*)((const bf16*)woutr + i);
      }
    }
  }
}

// ---------------------------------------------------------------- phase B: MFMA chunk-serial recurrence
// r16: grid 64 = h*4 + vq (32 v per block). Per-CU LDS traffic ~halved vs r15.
// Waves: mm2 -> wave w owns t-tile w; update -> wave w owns (v-tile w&1, k-tiles
// 2(w>>1)..+1), Sacc[2] persistent f32. State hi/lo bf16 in LDS (X8 swizzle).
// Per chunk: B1(syncthreads: drains prev stage+all) -> issue stage(c+1) ->
// KT build + batched frags -> 20 MFMA -> pack/stores -> B2(lgkmcnt-only raw
// barrier; prefetch stays in flight) -> batched S-update (8 MFMA) -> loop.
__global__ __launch_bounds__(256, 1)
void chunk_b(const bf16* __restrict__ qbuf, const bf16* __restrict__ kbuf,
             const float* __restrict__ gbuf, const bf16* __restrict__ dlocT,
             const bf16* __restrict__ whig, const bf16* __restrict__ wlog,
             bf16* __restrict__ dTg, bf16* __restrict__ o1g) {
  __shared__ __align__(16) char smem[114688];
  bf16* Wh  = (bf16*)(smem);             // [2][64][64] swz      16384 B
  bf16* Wl  = (bf16*)(smem + 16384);     // [2][64][64] swz
  bf16* Qs  = (bf16*)(smem + 32768);     // [2][64][64] swz
  bf16* Ks  = (bf16*)(smem + 49152);     // [2][64][64] linear
  bf16* Dls = (bf16*)(smem + 65536);     // [2][32][64] swz (dlocT slice) 8192 B
  bf16* KT  = (bf16*)(smem + 73728);     // [64][64] swz (K^T)   8192 B
  bf16* Shi = (bf16*)(smem + 81920);     // [32][64] swz         4096 B
  bf16* Slo = (bf16*)(smem + 86016);     // [32][64] swz
  bf16* Dth = (bf16*)(smem + 90112);     // [32][64] swz (fS-scaled deltaT hi)
  bf16* Dtl = (bf16*)(smem + 94208);     // [32][64] swz (lo)
  float* fSa = (float*)(smem + 98304);   // [32][64] e^{cumC-cum_t}  8192 B
  float* dSa = (float*)(smem + 106496);  // [32][64] e^{cum_t}

  const int t = threadIdx.x;
  const int h = blockIdx.x >> 2, vq = blockIdx.x & 3;
  const int lane = t & 63, w = t >> 6;
  const int r = lane & 15, q = lane >> 4;
  const int tb = w * 16 + q * 4;         // this lane's t-row base (mm2 C rows)

  auto stage = [&](int bb, int cc) {
    const long c16h = (long)(cc * 16 + h);
#pragma unroll
    for (int it = 0; it < 2; ++it) {
      int p = it * 256 + t;              // 16B-group id, 0..511
      int row = p >> 3, g = p & 7;
      int sg = ((g ^ (row & 7)) << 3);   // pre-swizzled source column
      GLDS16(whig + c16h * 4096 + row * 64 + sg, (char*)Wh + bb * 8192 + p * 16);
      GLDS16(wlog + c16h * 4096 + row * 64 + sg, (char*)Wl + bb * 8192 + p * 16);
      GLDS16(qbuf + (long)(cc * 64 + row) * KEY_DIM + h * DKv + sg, (char*)Qs + bb * 8192 + p * 16);
      GLDS16(kbuf + (long)(cc * 64 + row) * KEY_DIM + h * DKv + (g << 3), (char*)Ks + bb * 8192 + p * 16);
    }
    {  // Dls: [32][64] slice of dlocT, one iteration
      int row = t >> 3, g = t & 7;
      int sg = ((g ^ (row & 7)) << 3);
      GLDS16(dlocT + c16h * 8192 + (long)(vq * 32 + row) * 64 + sg,
             (char*)Dls + bb * 4096 + t * 16);
    }
  };

  // prologue: one-time decay tables for ALL 32 chunks (wave w -> chunks w*8..w*8+7)
  {
    float g8[8];
#pragma unroll
    for (int i = 0; i < 8; ++i)
      g8[i] = gbuf[(long)((w * 8 + i) * 64 + lane) * NH + h];
#pragma unroll
    for (int i = 0; i < 8; ++i) {
      float cs = g8[i];
#pragma unroll
      for (int d = 1; d < 64; d <<= 1) { float y = __shfl_up(cs, d); if (lane >= d) cs += y; }
      float tot = __shfl(cs, 63);
      fSa[(w * 8 + i) * 64 + lane] = __expf(tot - cs);
      dSa[(w * 8 + i) * 64 + lane] = __expf(cs);
    }
  }
  {
    f32x4 z = {0.f, 0.f, 0.f, 0.f};
    ((f32x4*)Shi)[t] = z;
    ((f32x4*)Slo)[t] = z;
  }
  stage(0, 0);
  f32x4 Sacc[2] = {};   // this wave's (v-tile w&1, k-tiles 2(w>>1)+m)

  const int va = w & 1, kt0 = (w >> 1) * 2;   // update-phase ownership

  for (int c = 0; c < 32; ++c) {
    const int buf = c & 1, nb = buf ^ 1;
    __syncthreads();   // B1: stage[buf] + all LDS writes drained (vmcnt+lgkmcnt)
    if (c < 31) stage(nb, c + 1);   // prefetch: in flight across B2, drained at next B1
    const bf16* wh = Wh + buf * 4096;
    const bf16* wl = Wl + buf * 4096;
    const bf16* qs = Qs + buf * 4096;
    const bf16* ks = Ks + buf * 4096;
    const bf16* dls = Dls + buf * 2048;
    const float* fS = fSa + c * 64;
    const float* dS = dSa + c * 64;
    const long gch = (long)(c * 16 + h) * 8192 + (long)(vq * 32) * 64;

    // K^T build (swizzled): lane k, rows i = w*16..w*16+15 (update-only)
    if (c < 31) {
      const int k2 = lane;
#pragma unroll
      for (int ii = 0; ii < 16; ++ii) {
        const int i = w * 16 + ii;
        const int pg = (i >> 3) ^ (k2 & 7);
        KT[k2 * 64 + pg * 8 + (i & 7)] = ks[i * 64 + k2];
      }
    }

    // hoisted decay factors for this lane's 4 t-rows
    float fs4[4], ds4[4];
#pragma unroll
    for (int rr = 0; rr < 4; ++rr) { fs4[rr] = fS[tb + rr]; ds4[rr] = dS[tb + rr]; }

    // ---- batched fragment loads ----
    bf16x8 wahi[2], walo[2], qa[2];
#pragma unroll
    for (int kk = 0; kk < 2; ++kk) {
      const int row = w * 16 + r;
      const int g = (kk * 4 + q) ^ (row & 7);
      wahi[kk] = *(const bf16x8*)(wh + row * 64 + g * 8);
      walo[kk] = *(const bf16x8*)(wl + row * 64 + g * 8);
      qa[kk]   = *(const bf16x8*)(qs + row * 64 + g * 8);
    }
    bf16x8 sh[2][2], sl[2][2];
#pragma unroll
    for (int n = 0; n < 2; ++n)
#pragma unroll
      for (int kk = 0; kk < 2; ++kk) {
        const int vrow = n * 16 + r;
        const int g = (kk * 4 + q) ^ (vrow & 7);
        sh[n][kk] = *(const bf16x8*)(Shi + vrow * 64 + g * 8);
        sl[n][kk] = *(const bf16x8*)(Slo + vrow * 64 + g * 8);
      }
    float dl4[2][4];
#pragma unroll
    for (int n = 0; n < 2; ++n) {
      const int vloc = n * 16 + r;
      const int pg = (tb >> 3) ^ (vloc & 7);
      bf16x4 dv4 = *(const bf16x4*)(dls + vloc * 64 + pg * 8 + (tb & 7));
#pragma unroll
      for (int rr = 0; rr < 4; ++rr) dl4[n][rr] = (float)dv4[rr];
    }

    // ---- 20 MFMA, 4 independent chains ----
    f32x4 da[2] = {}, oa[2] = {};
#pragma unroll
    for (int n = 0; n < 2; ++n)
#pragma unroll
      for (int kk = 0; kk < 2; ++kk) {
        da[n] = __builtin_amdgcn_mfma_f32_16x16x32_bf16(wahi[kk], sh[n][kk], da[n], 0, 0, 0);
        da[n] = __builtin_amdgcn_mfma_f32_16x16x32_bf16(wahi[kk], sl[n][kk], da[n], 0, 0, 0);
        da[n] = __builtin_amdgcn_mfma_f32_16x16x32_bf16(walo[kk], sh[n][kk], da[n], 0, 0, 0);
        oa[n] = __builtin_amdgcn_mfma_f32_16x16x32_bf16(qa[kk],   sh[n][kk], oa[n], 0, 0, 0);
        oa[n] = __builtin_amdgcn_mfma_f32_16x16x32_bf16(qa[kk],   sl[n][kk], oa[n], 0, 0, 0);
      }

    // ---- pack + stores (Dl added here instead of C-init: same sum) ----
#pragma unroll
    for (int n = 0; n < 2; ++n) {
      const int vloc = n * 16 + r;
      bf16x4 dpk, opk, fhk, flk;
#pragma unroll
      for (int rr = 0; rr < 4; ++rr) {
        float dv = dl4[n][rr] + da[n][rr];
        dpk[rr] = (bf16)dv;
        float p = fs4[rr] * dv;
        bf16 ph = (bf16)p;
        fhk[rr] = ph;
        flk[rr] = (bf16)(p - (float)ph);
        opk[rr] = (bf16)(ds4[rr] * oa[n][rr]);
      }
      *(bf16x4*)(dTg + gch + (long)vloc * 64 + tb) = dpk;
      *(bf16x4*)(o1g + gch + (long)vloc * 64 + tb) = opk;
      const int pg = (tb >> 3) ^ (vloc & 7);
      *(bf16x4*)(Dth + vloc * 64 + pg * 8 + (tb & 7)) = fhk;
      *(bf16x4*)(Dtl + vloc * 64 + pg * 8 + (tb & 7)) = flk;
    }

    // B2: LDS-only barrier (Dth/Dtl/KT visible). NO vmcnt drain: prefetch + global
    // stores remain in flight through the S-update and drain at the next B1.
    asm volatile("s_waitcnt lgkmcnt(0)" ::: "memory");
    __builtin_amdgcn_sched_barrier(0);
    __builtin_amdgcn_s_barrier();
    __builtin_amdgcn_sched_barrier(0);

    if (c < 31) {
      // update: S' = dC*S + DltT(hi/lo) x KT  [wave: v-tile va, k-tiles kt0..kt0+1]
      const float dC = dS[63];
      bf16x8 dh[2], dlo2[2], ktf[2][2];
#pragma unroll
      for (int kk = 0; kk < 2; ++kk) {
        const int vrow = va * 16 + r;
        const int g = (kk * 4 + q) ^ (vrow & 7);
        dh[kk]   = *(const bf16x8*)(Dth + vrow * 64 + g * 8);
        dlo2[kk] = *(const bf16x8*)(Dtl + vrow * 64 + g * 8);
      }
#pragma unroll
      for (int m = 0; m < 2; ++m)
#pragma unroll
        for (int kk = 0; kk < 2; ++kk) {
          const int krow = (kt0 + m) * 16 + r;
          const int g = (kk * 4 + q) ^ (krow & 7);
          ktf[m][kk] = *(const bf16x8*)(KT + krow * 64 + g * 8);
        }
#pragma unroll
      for (int m = 0; m < 2; ++m) {
        f32x4 sa;
#pragma unroll
        for (int rr = 0; rr < 4; ++rr) sa[rr] = dC * Sacc[m][rr];
#pragma unroll
        for (int kk = 0; kk < 2; ++kk) {
          sa = __builtin_amdgcn_mfma_f32_16x16x32_bf16(dh[kk],   ktf[m][kk], sa, 0, 0, 0);
          sa = __builtin_amdgcn_mfma_f32_16x16x32_bf16(dlo2[kk], ktf[m][kk], sa, 0, 0, 0);
        }
        Sacc[m] = sa;
        // write S hi/lo (swizzled scalar stores): elems (v = va*16+q*4+rr, k)
        const int k = (kt0 + m) * 16 + r;
#pragma unroll
        for (int rr = 0; rr < 4; ++rr) {
          const int v = va * 16 + q * 4 + rr;
          float s = sa[rr];
          bf16 hh = (bf16)s;
          const int pg = (k >> 3) ^ (v & 7);
          Shi[v * 64 + pg * 8 + (k & 7)] = hh;
          Slo[v * 64 + pg * 8 + (k & 7)] = (bf16)(s - (float)hh);
        }
      }
    }
  }
}

// ---------------------------------------------------------------- phase C: outputs, MFMA
// grid 512 = c*16 + h.  O[t][v] = o1[v][t] + sum_i P[t][i] delta^T[v][i]
__global__ __launch_bounds__(256, 2)
void chunk_c(const bf16* __restrict__ qbuf, const bf16* __restrict__ kbuf,
             const float* __restrict__ gbuf, const bf16* __restrict__ dTg,
             const bf16* __restrict__ o1g, bf16* __restrict__ core) {
  // Qs@0 8K | Ks@8192 8K | Pl@16384 8K | dT@24576 16K | o1l@40960 16K | cum@57344
  __shared__ __align__(16) char smem[57600];
  const int t = threadIdx.x;
  const int c = blockIdx.x >> 4, h = blockIdx.x & 15;
  const long c16h = (long)(c * 16 + h);
  bf16* Qs  = (bf16*)smem;
  bf16* Ksl = (bf16*)(smem + 8192);
  bf16* Pl  = (bf16*)(smem + 16384);
  const bf16* dT  = (const bf16*)(smem + 24576);
  const bf16* o1l = (const bf16*)(smem + 40960);
  float* cumS = (float*)(smem + 57344);

#pragma unroll
  for (int it = 0; it < 2; ++it) {
    int byte = (it * 256 + t) * 16;
    int row = byte >> 7, col = (byte & 127) >> 1;
    GLDS16(qbuf + (long)(c * 64 + row) * KEY_DIM + h * DKv + col, smem + byte);
    GLDS16(kbuf + (long)(c * 64 + row) * KEY_DIM + h * DKv + col, smem + 8192 + byte);
  }
#pragma unroll
  for (int it = 0; it < 4; ++it) {
    int byte = (it * 256 + t) * 16;
    GLDS16(dTg + c16h * 8192 + (byte >> 1), smem + 24576 + byte);
    GLDS16(o1g + c16h * 8192 + (byte >> 1), smem + 40960 + byte);
  }
  if (t < 64) {
    float cc = gbuf[(long)(c * 64 + t) * NH + h];
#pragma unroll
    for (int d = 1; d < 64; d <<= 1) { float y = __shfl_up(cc, d); if (t >= d) cc += y; }
    cumS[t] = cc;
  }
  __syncthreads();

  const int lane = t & 63, wv = t >> 6;
  const int r = lane & 15, q = lane >> 4;
  const bf16x8* Qs8 = (const bf16x8*)Qs;
  const bf16x8* Ks8 = (const bf16x8*)Ksl;

  // c1: P[t][i] = (i<=t) ? e^{cum_t-cum_i} (q_t.k_i) : 0
#pragma unroll
  for (int n = 0; n < 4; ++n) {
    f32x4 acc = {0.f, 0.f, 0.f, 0.f};
#pragma unroll
    for (int kk = 0; kk < 2; ++kk)
      acc = __builtin_amdgcn_mfma_f32_16x16x32_bf16(
          Qs8[(wv * 16 + r) * 8 + kk * 4 + q], Ks8[(n * 16 + r) * 8 + kk * 4 + q], acc, 0, 0, 0);
    const int i = n * 16 + r;
#pragma unroll
    for (int rr = 0; rr < 4; ++rr) {
      const int tr = wv * 16 + q * 4 + rr;
      Pl[tr * 64 + i] = (i <= tr) ? (bf16)(__expf(cumS[tr] - cumS[i]) * acc[rr]) : (bf16)0.0f;
    }
  }
  __syncthreads();

  // c2: O = o1 (acc init) + P.deltaT via MFMA
  {
    const bf16x8* Pl8 = (const bf16x8*)Pl;
    const bf16x8* dT8 = (const bf16x8*)dT;
    bf16x8 pf[2];
#pragma unroll
    for (int kk = 0; kk < 2; ++kk) pf[kk] = Pl8[(wv * 16 + r) * 8 + kk * 4 + q];
#pragma unroll
    for (int n = 0; n < 8; ++n) {
      const int v = n * 16 + r;
      f32x4 acc;
#pragma unroll
      for (int rr = 0; rr < 4; ++rr)
        acc[rr] = (float)o1l[v * 64 + (wv * 16 + q * 4 + rr)];
#pragma unroll
      for (int kk = 0; kk < 2; ++kk)
        acc = __builtin_amdgcn_mfma_f32_16x16x32_bf16(
            pf[kk], dT8[(n * 16 + r) * 8 + kk * 4 + q], acc, 0, 0, 0);
#pragma unroll
      for (int rr = 0; rr < 4; ++rr) {
        const int tr = wv * 16 + q * 4 + rr;
        core[(long)(c * 64 + tr) * VAL_DIM + h * DVv + v] = (bf16)acc[rr];
      }
    }
  }
}

// ---------------------------------------------------------------- RMSNorm + SiLU(z) gate
__global__ __launch_bounds__(256)
void gate_norm(const bf16* __restrict__ core, const bf16* __restrict__ zb,
               const void* __restrict__ normwr, bf16* __restrict__ gated,
               const unsigned* __restrict__ flagp) {
  const bool f32g = (*flagp != 0);
  const int s  = blockIdx.x;
  const int t  = threadIdx.x;
  const int h  = t >> 4;
  const int li = t & 15;
  const long base = (long)s * VAL_DIM + h * DVv + li * 8;
  bf16x8 c8 = *(const bf16x8*)(core + base);
  bf16x8 z8 = *(const bf16x8*)(zb + base);
  float x[8], z[8], nw[8];
  float ss = 0.f;
#pragma unroll
  for (int j = 0; j < 8; ++j) { x[j] = (float)c8[j]; z[j] = (float)z8[j]; ss += x[j] * x[j]; }
  if (f32g) {
    const float* np_ = (const float*)normwr + li * 8;
#pragma unroll
    for (int j = 0; j < 8; ++j) nw[j] = np_[j];
  } else {
    const u16* np_ = (const u16*)normwr + li * 8;
#pragma unroll
    for (int j = 0; j < 8; ++j) nw[j] = b2f(np_[j]);
  }
  ss += __shfl_xor(ss, 1); ss += __shfl_xor(ss, 2);
  ss += __shfl_xor(ss, 4); ss += __shfl_xor(ss, 8);
  float scale = rsqrtf(ss * (1.f / 128.f) + 1e-6f);
#pragma unroll
  for (int j = 0; j < 8; ++j) {
    float y = x[j] * scale * nw[j];
    y *= z[j] * sigmoidf_(z[j]);
    gated[base + j] = (bf16)y;
  }
}

// ---------------------------------------------------------------- launcher
extern "C" void kernel_launch(void* const* d_in, const int* in_sizes, int n_in,
                              void* d_out, int out_size, void* d_ws, size_t ws_size,
                              hipStream_t stream) {
  char* ws = (char*)d_ws;
  const bool big = ws_size >= ((48u << 20) + (512u << 10));

  if (big) {
    // ws: [0,8M) hsb -> dTg | [8,16M) wqkvb/wzb -> o1g | [16,24M) wqkvb -> zbuf
    //     [24,28M) mixed -> whig | [28,32M) mixed -> wlog | [32,40M) mixed -> woutb
    //     [40,44M) qbuf | [44,48M) kbuf -> (with qbuf) gated | [48M..) eg|beta|g|flag
    // d_out: [0,8M) vbuf -> core | [8,16M) dlocT; final gemm overwrites all 16M f32.
    bf16*  hsb   = (bf16*)ws;
    bf16*  wqkvb = (bf16*)(ws + (8u << 20));
    bf16*  wzb   = (bf16*)(ws + (8u << 20));
    bf16*  zbuf  = (bf16*)(ws + (16u << 20));
    bf16*  mixed = (bf16*)(ws + (24u << 20));
    bf16*  whig  = (bf16*)(ws + (24u << 20));
    bf16*  wlog  = (bf16*)(ws + (28u << 20));
    bf16*  woutb = (bf16*)(ws + (32u << 20));
    bf16*  qbuf  = (bf16*)(ws + (40u << 20));
    bf16*  kbuf  = (bf16*)(ws + (44u << 20));
    bf16*  gated = (bf16*)(ws + (40u << 20));
    bf16*  dTg   = (bf16*)ws;
    bf16*  o1g   = (bf16*)(ws + (8u << 20));
    float* egp  = (float*)(ws + (48u << 20));
    float* betp = (float*)(ws + (48u << 20) + (128u << 10));
    float* gbp  = (float*)(ws + (48u << 20) + (256u << 10));
    unsigned* flagp = (unsigned*)(ws + (48u << 20) + (384u << 10));
    bf16* vbuf  = (bf16*)d_out;
    bf16* dlocp = (bf16*)((char*)d_out + (8u << 20));
    bf16* corep = (bf16*)d_out;

    detect_dtype<<<1, 64, 0, stream>>>((const u16*)d_in[0], flagp);
    proj_ab<<<SEQ / 8, 256, 0, stream>>>(d_in[0], d_in[2], d_in[3], d_in[6], d_in[7], egp, betp, gbp, flagp);
    cvt_bf16<<<(SEQ * HIDDEN) / 2048, 256, 0, stream>>>(d_in[0], hsb, (long)SEQ * HIDDEN, flagp);
    cvt_bf16<<<(CONV_DIM * HIDDEN) / 2048, 256, 0, stream>>>(d_in[1], wqkvb, (long)CONV_DIM * HIDDEN, flagp);
    gemm_nt<false><<<dim3(CONV_DIM / 128, SEQ / 128), 256, 0, stream>>>(hsb, wqkvb, mixed, CONV_DIM, HIDDEN, flagp, 0, 0);
    cvt_bf16<<<(VAL_DIM * HIDDEN) / 2048, 256, 0, stream>>>(d_in[4], wzb, (long)VAL_DIM * HIDDEN, flagp);
    conv_norm<<<dim3(SEQ, CONV_DIM / 256), 256, 0, stream>>>(mixed, d_in[5], qbuf, kbuf, vbuf, flagp);
    chunk_a<<<512 + 256 + 2048, 256, 0, stream>>>(kbuf, vbuf, gbp, betp, dlocp, whig, wlog,
                                                  hsb, wzb, zbuf, d_in[9], woutb, flagp);
    chunk_b<<<64, 256, 0, stream>>>(qbuf, kbuf, gbp, dlocp, whig, wlog, dTg, o1g);
    chunk_c<<<512, 256, 0, stream>>>(qbuf, kbuf, gbp, dTg, o1g, corep);
    gate_norm<<<SEQ, 256, 0, stream>>>(corep, zbuf, d_in[8], gated, flagp);
    gemm_nt<true><<<dim3(HIDDEN / 128, SEQ / 128), 256, 0, stream>>>(gated, woutb, d_out, HIDDEN, VAL_DIM, flagp, 0, 0);
  } else {
    // Fallback layout (peak 24.26 MiB): r6-style staging GEMMs; per-step scan.
    bf16* mixed = (bf16*)ws;
    bf16* qbuf  = (bf16*)(ws + (16u << 20));
    bf16* kbuf  = (bf16*)(ws + (20u << 20));
    bf16* zbuf  = (bf16*)ws;
    bf16* corep = (bf16*)(ws + (8u << 20));
    bf16* gated = (bf16*)(ws + (16u << 20));
    float* egp  = (float*)(ws + (24u << 20));
    float* betp = (float*)(ws + (24u << 20) + (128u << 10));
    unsigned* flagp = (unsigned*)(ws + (24u << 20) + (256u << 10));
    bf16* vbuf  = (bf16*)d_out;

    detect_dtype<<<1, 64, 0, stream>>>((const u16*)d_in[0], flagp);
    proj_ab<<<SEQ / 8, 256, 0, stream>>>(d_in[0], d_in[2], d_in[3], d_in[6], d_in[7], egp, betp, nullptr, flagp);
    gemm_nt<false><<<dim3(CONV_DIM / 128, SEQ / 128), 256, 0, stream>>>(d_in[0], d_in[1], mixed, CONV_DIM, HIDDEN, flagp, 1, 1);
    conv_norm<<<dim3(SEQ, CONV_DIM / 256), 256, 0, stream>>>(mixed, d_in[5], qbuf, kbuf, vbuf, flagp);
    gemm_nt<false><<<dim3(VAL_DIM / 128, SEQ / 128), 256, 0, stream>>>(d_in[0], d_in[4], zbuf, VAL_DIM, HIDDEN, flagp, 1, 1);
    fused_scan<<<128, 256, 0, stream>>>(qbuf, kbuf, vbuf, egp, betp, corep,
                                        nullptr, nullptr, nullptr, nullptr, nullptr, flagp,
                                        128, 0);
    gate_norm<<<SEQ, 256, 0, stream>>>(corep, zbuf, d_in[8], gated, flagp);
    gemm_nt<true><<<dim3(HIDDEN / 128, SEQ / 128), 256, 0, stream>>>(gated, d_in[9], d_out, HIDDEN, VAL_DIM, flagp, 0, 1);
  }
}

// Round 8
// 475.382 us; speedup vs baseline: 1.0501x; 1.0501x over previous
//
#include <hip/hip_runtime.h>
#include <stdint.h>

// LinearAttention (gated delta rule), S=2048, HID=2048, H=16, DK=64, DV=128, conv K=4.
// r18 == r17 resubmit (previous bench died to infra: "container failed twice"; kernel
// never executed). GEMM consolidation + 2-phase dbuf:
//   (1) QKV+z merged into ONE wide gemm (N=6144, A=hsb shared), grid 768,
//       epilogue splits mixed/zbuf per 128-col tile; chunk_a is scan+cvt only.
//   (2) T3-minimum 2-phase double-buffer in both GEMMs (stage(t+1) before compute(t),
//       ONE barrier/K-step) - catalog-proven +10%, accumulation order unchanged.
// Buffer schedule (verified disjoint in time):
//   ws: [0,8) hsb -> vbuf -> dTg | [8,24) wcomb(qkv) -> woutb[8,16)+o1g[16,24)
//       [24,32) wcomb(z) -> whig[24,28)+wlog[28,32) | [32,40) zbuf
//       [40,48) qbuf+kbuf -> gated | [48M..) eg|beta|g|flag
//   d_out: [0,16) mixed -> core[0,8)+dlocT[8,16) -> final f32 out.

#define SEQ 2048
#define HIDDEN 2048
#define NH 16
#define DKv 64
#define DVv 128
#define KEY_DIM 1024
#define VAL_DIM 2048
#define CONV_DIM 4096

typedef __bf16 bf16;
typedef unsigned short u16;
typedef __attribute__((ext_vector_type(8))) __bf16 bf16x8;
typedef __attribute__((ext_vector_type(4))) __bf16 bf16x4;
typedef __attribute__((ext_vector_type(4))) float f32x4;

#define AS1 __attribute__((address_space(1)))
#define AS3 __attribute__((address_space(3)))
#define GLDS16(src, dst) __builtin_amdgcn_global_load_lds((AS1 const void*)(src), (AS3 void*)(dst), 16, 0, 0)

__device__ __forceinline__ float b2f(u16 u) {
  union { unsigned int i; float f; } c; c.i = ((unsigned int)u) << 16; return c.f;
}
__device__ __forceinline__ float sigmoidf_(float x) { return 1.0f / (1.0f + __expf(-x)); }

// ---------------------------------------------------------------- dtype detector
__global__ void detect_dtype(const u16* __restrict__ p, unsigned* __restrict__ flag) {
  int lane = threadIdx.x;  // 64 threads
  int cnt = 0;
  for (int w = lane; w < 2048; w += 64) {
    unsigned e = (p[2 * w] >> 7) & 0xFF;
    if (e < 64) cnt++;
  }
  cnt += __shfl_xor(cnt, 1);  cnt += __shfl_xor(cnt, 2);  cnt += __shfl_xor(cnt, 4);
  cnt += __shfl_xor(cnt, 8);  cnt += __shfl_xor(cnt, 16); cnt += __shfl_xor(cnt, 32);
  if (lane == 0) *flag = (cnt > 64) ? 1u : 0u;   // 1 = inputs are f32
}

// ---------------------------------------------------------------- f32 -> bf16 convert
__global__ __launch_bounds__(256)
void cvt_bf16(const void* __restrict__ src, bf16* __restrict__ dst, long n,
              const unsigned* __restrict__ flagp) {
  long i = ((long)blockIdx.x * 256 + threadIdx.x) * 8;
  if (i >= n) return;
  if (*flagp) {
    const f32x4* s = (const f32x4*)((const float*)src + i);
    f32x4 a = s[0], b = s[1];
    bf16x8 o;
#pragma unroll
    for (int j = 0; j < 4; ++j) { o[j] = (bf16)a[j]; o[4 + j] = (bf16)b[j]; }
    *(bf16x8*)(dst + i) = o;
  } else {
    *(bf16x8*)(dst + i) = *(const bf16x8*)((const bf16*)src + i);
  }
}

// ---------------------------------------------------------------- GEMM (NT) standalone, 2-phase dbuf
template<bool F32OUT>
__global__ __launch_bounds__(256, 2)
void gemm_nt(const void* __restrict__ Araw, const void* __restrict__ Braw,
             void* __restrict__ Cv, int N, int K,
             const unsigned* __restrict__ flagp, int useA, int useB) {
  __shared__ __align__(16) bf16 As[2][128 * 32];
  __shared__ __align__(16) bf16 Bs[2][128 * 32];
  const bool f32g = (*flagp != 0);
  const bool fA = useA && f32g;
  const bool fB = useB && f32g;
  const int tid  = threadIdx.x;
  const int lane = tid & 63;
  const int wv   = tid >> 6;
  const int wm   = (wv & 1) << 6;
  const int wn   = (wv >> 1) << 6;
  const long bm  = (long)blockIdx.y * 128;
  const long bn  = (long)blockIdx.x * 128;

  f32x4 acc[4][4] = {};

  auto stage = [&](int bb, int k0) {
#pragma unroll
    for (int it = 0; it < 2; ++it) {
      int e   = (it * 256 + tid) * 8;
      int row = e >> 5;
      int col = e & 31;
      long offA = (bm + row) * (long)K + (k0 + col);
      long offB = (bn + row) * (long)K + (k0 + col);
      if (fA) {
        const float* g = (const float*)Araw + offA;
        f32x4 u0 = *(const f32x4*)g, u1 = *(const f32x4*)(g + 4);
        bf16x8 bv;
#pragma unroll
        for (int j = 0; j < 4; ++j) { bv[j] = (bf16)u0[j]; bv[4 + j] = (bf16)u1[j]; }
        *(bf16x8*)&As[bb][e] = bv;
      } else {
        GLDS16((const bf16*)Araw + offA, &As[bb][e]);
      }
      if (fB) {
        const float* g = (const float*)Braw + offB;
        f32x4 u0 = *(const f32x4*)g, u1 = *(const f32x4*)(g + 4);
        bf16x8 bv;
#pragma unroll
        for (int j = 0; j < 4; ++j) { bv[j] = (bf16)u0[j]; bv[4 + j] = (bf16)u1[j]; }
        *(bf16x8*)&Bs[bb][e] = bv;
      } else {
        GLDS16((const bf16*)Braw + offB, &Bs[bb][e]);
      }
    }
  };

  stage(0, 0);
  __syncthreads();
  int buf = 0;
  const int r = lane & 15, q = lane >> 4;
  const int nk = K >> 5;
  for (int ks = 0; ks < nk; ++ks) {
    if (ks + 1 < nk) stage(buf ^ 1, (ks + 1) * 32);   // prefetch under compute
    const bf16x8* As8 = (const bf16x8*)As[buf];
    const bf16x8* Bs8 = (const bf16x8*)Bs[buf];
    bf16x8 af[4], bfr[4];
#pragma unroll
    for (int i = 0; i < 4; ++i) af[i]  = As8[(wm + i * 16 + r) * 4 + q];
#pragma unroll
    for (int j = 0; j < 4; ++j) bfr[j] = Bs8[(wn + j * 16 + r) * 4 + q];
#pragma unroll
    for (int i = 0; i < 4; ++i)
#pragma unroll
      for (int j = 0; j < 4; ++j)
        acc[i][j] = __builtin_amdgcn_mfma_f32_16x16x32_bf16(af[i], bfr[j], acc[i][j], 0, 0, 0);
    __syncthreads();   // drains prefetch DMA (flew under MFMA) + guards buf reuse
    buf ^= 1;
  }

#pragma unroll
  for (int i = 0; i < 4; ++i)
#pragma unroll
    for (int j = 0; j < 4; ++j) {
      long row = bm + wm + i * 16 + q * 4;
      long col = bn + wn + j * 16 + r;
#pragma unroll
      for (int rr = 0; rr < 4; ++rr) {
        if constexpr (F32OUT) ((float*)Cv)[(row + rr) * N + col] = acc[i][j][rr];
        else                  ((bf16*)Cv)[(row + rr) * N + col] = (bf16)acc[i][j][rr];
      }
    }
}

// ---------------------------------------------------------------- combined QKV+Z GEMM (bf16, dbuf, split epilogue)
// A = hsb [2048][2048], B = wcomb [6144][2048] (rows 0-4095 = wqkv, 4096-6143 = wz).
// C cols 0-4095 -> mixed (stride 4096), cols 4096-6143 -> zbuf (stride 2048).
__global__ __launch_bounds__(256, 2)
void gemm_qkvz(const bf16* __restrict__ A, const bf16* __restrict__ B,
               bf16* __restrict__ Cmixed, bf16* __restrict__ Cz) {
  __shared__ __align__(16) bf16 As[2][128 * 32];
  __shared__ __align__(16) bf16 Bs[2][128 * 32];
  const int tid  = threadIdx.x;
  const int lane = tid & 63;
  const int wv   = tid >> 6;
  const int wm   = (wv & 1) << 6;
  const int wn   = (wv >> 1) << 6;
  const long bm  = (long)blockIdx.y * 128;
  const long bn  = (long)blockIdx.x * 128;
  const int K = HIDDEN;

  f32x4 acc[4][4] = {};

  auto stage = [&](int bb, int k0) {
#pragma unroll
    for (int it = 0; it < 2; ++it) {
      int e = (it * 256 + tid) * 8;
      int row = e >> 5, col = e & 31;
      GLDS16(A + (bm + row) * (long)K + k0 + col, &As[bb][e]);
      GLDS16(B + (bn + row) * (long)K + k0 + col, &Bs[bb][e]);
    }
  };

  stage(0, 0);
  __syncthreads();
  int buf = 0;
  const int r = lane & 15, q = lane >> 4;
  const int nk = K >> 5;
  for (int ks = 0; ks < nk; ++ks) {
    if (ks + 1 < nk) stage(buf ^ 1, (ks + 1) * 32);
    const bf16x8* As8 = (const bf16x8*)As[buf];
    const bf16x8* Bs8 = (const bf16x8*)Bs[buf];
    bf16x8 af[4], bfr[4];
#pragma unroll
    for (int i = 0; i < 4; ++i) af[i]  = As8[(wm + i * 16 + r) * 4 + q];
#pragma unroll
    for (int j = 0; j < 4; ++j) bfr[j] = Bs8[(wn + j * 16 + r) * 4 + q];
#pragma unroll
    for (int i = 0; i < 4; ++i)
#pragma unroll
      for (int j = 0; j < 4; ++j)
        acc[i][j] = __builtin_amdgcn_mfma_f32_16x16x32_bf16(af[i], bfr[j], acc[i][j], 0, 0, 0);
    __syncthreads();
    buf ^= 1;
  }

  const bool isz = (bn >= 4096);
  bf16* Cp = isz ? Cz : Cmixed;
  const long cstride = isz ? 2048 : 4096;
  const long cb = (isz ? (bn - 4096) : bn) + wn;
#pragma unroll
  for (int i = 0; i < 4; ++i)
#pragma unroll
    for (int j = 0; j < 4; ++j) {
      long row = bm + wm + i * 16 + q * 4;
      long col = cb + j * 16 + r;
#pragma unroll
      for (int rr = 0; rr < 4; ++rr)
        Cp[(row + rr) * cstride + col] = (bf16)acc[i][j][rr];
    }
}

// ---------------------------------------------------------------- GEMM body (bf16-only, fallback fused)
__device__ void gemm_body_bf16(char* smemc, const bf16* __restrict__ A,
                               const bf16* __restrict__ B, bf16* __restrict__ C,
                               int N, int K, int bx, int by, int tid) {
  bf16* As = (bf16*)smemc;             // 8 KiB
  bf16* Bs = (bf16*)(smemc + 8192);    // 8 KiB
  const int lane = tid & 63;
  const int wv = tid >> 6, wm = (wv & 1) << 6, wn = (wv >> 1) << 6;
  const long bm = (long)by * 128, bn = (long)bx * 128;
  f32x4 acc[4][4] = {};
  for (int k0 = 0; k0 < K; k0 += 32) {
#pragma unroll
    for (int it = 0; it < 2; ++it) {
      int e = (it * 256 + tid) * 8;
      int row = e >> 5, col = e & 31;
      const bf16* gA = A + (bm + row) * (long)K + k0 + col;
      const bf16* gB = B + (bn + row) * (long)K + k0 + col;
      GLDS16(gA, &As[e]);
      GLDS16(gB, &Bs[e]);
    }
    __syncthreads();
    const bf16x8* As8 = (const bf16x8*)As;
    const bf16x8* Bs8 = (const bf16x8*)Bs;
    const int r = lane & 15, q = lane >> 4;
    bf16x8 af[4], bfr[4];
#pragma unroll
    for (int i = 0; i < 4; ++i) af[i]  = As8[(wm + i * 16 + r) * 4 + q];
#pragma unroll
    for (int j = 0; j < 4; ++j) bfr[j] = Bs8[(wn + j * 16 + r) * 4 + q];
#pragma unroll
    for (int i = 0; i < 4; ++i)
#pragma unroll
      for (int j = 0; j < 4; ++j)
        acc[i][j] = __builtin_amdgcn_mfma_f32_16x16x32_bf16(af[i], bfr[j], acc[i][j], 0, 0, 0);
    __syncthreads();
  }
  const int r = lane & 15, q = lane >> 4;
#pragma unroll
  for (int i = 0; i < 4; ++i)
#pragma unroll
    for (int j = 0; j < 4; ++j) {
      long row = bm + wm + i * 16 + q * 4;
      long col = bn + wn + j * 16 + r;
#pragma unroll
      for (int rr = 0; rr < 4; ++rr)
        C[(row + rr) * (long)N + col] = (bf16)acc[i][j][rr];
    }
}

// ---------------------------------------------------------------- a/b proj -> exp(g), g, beta
__global__ __launch_bounds__(256)
void proj_ab(const void* __restrict__ hsr, const void* __restrict__ War,
             const void* __restrict__ Wbr, const void* __restrict__ A_logr,
             const void* __restrict__ dtbr,
             float* __restrict__ eg, float* __restrict__ bet,
             float* __restrict__ gb,
             const unsigned* __restrict__ flagp) {
  const bool f32g = (*flagp != 0);
  const int t  = threadIdx.x;
  const int sl = t >> 5;
  const int o  = t & 31;
  const int h  = o & 15;
  const long s = (long)blockIdx.x * 8 + sl;
  float a0 = 0.f, a1 = 0.f, a2 = 0.f, a3 = 0.f;
  if (f32g) {
    const f32x4* x4 = (const f32x4*)((const float*)hsr + s * HIDDEN);
    const f32x4* w4 = (const f32x4*)((const float*)((o < 16) ? War : Wbr) + (long)h * HIDDEN);
#pragma unroll 8
    for (int k4 = 0; k4 < 512; ++k4) {
      f32x4 xv = x4[k4], wv = w4[k4];
      a0 = fmaf(xv[0], wv[0], a0);
      a1 = fmaf(xv[1], wv[1], a1);
      a2 = fmaf(xv[2], wv[2], a2);
      a3 = fmaf(xv[3], wv[3], a3);
    }
  } else {
    const bf16x8* x8 = (const bf16x8*)((const bf16*)hsr + s * HIDDEN);
    const bf16x8* w8 = (const bf16x8*)((const bf16*)((o < 16) ? War : Wbr) + (long)h * HIDDEN);
#pragma unroll 8
    for (int k8 = 0; k8 < 256; ++k8) {
      bf16x8 xv = x8[k8], wv = w8[k8];
      a0 += (float)xv[0] * (float)wv[0] + (float)xv[4] * (float)wv[4];
      a1 += (float)xv[1] * (float)wv[1] + (float)xv[5] * (float)wv[5];
      a2 += (float)xv[2] * (float)wv[2] + (float)xv[6] * (float)wv[6];
      a3 += (float)xv[3] * (float)wv[3] + (float)xv[7] * (float)wv[7];
    }
  }
  const float a = (a0 + a1) + (a2 + a3);
  if (o < 16) {
    float alog = f32g ? ((const float*)A_logr)[h] : b2f(((const u16*)A_logr)[h]);
    float dtb  = f32g ? ((const float*)dtbr)[h]   : b2f(((const u16*)dtbr)[h]);
    float xx = a + dtb;
    float sp = fmaxf(xx, 0.f) + log1pf(__expf(-fabsf(xx)));   // stable softplus
    float gg = -__expf(alog) * sp;                             // log-decay
    if (gb) gb[s * NH + h] = gg;
    eg[s * NH + h] = __expf(gg);
  } else {
    bet[s * NH + h] = sigmoidf_(a);
  }
}

// ---------------------------------------------------------------- conv + SiLU + l2norm
__global__ __launch_bounds__(256)
void conv_norm(const bf16* __restrict__ mixed, const void* __restrict__ convwr,
               bf16* __restrict__ qbuf, bf16* __restrict__ kbuf, bf16* __restrict__ vbuf,
               const unsigned* __restrict__ flagp) {
  const bool f32g = (*flagp != 0);
  const int s = blockIdx.x;
  const int c = blockIdx.y * 256 + threadIdx.x;
  float w0, w1, w2, w3;
  if (f32g) {
    const float* wp = (const float*)convwr + (long)c * 4;
    w0 = wp[0]; w1 = wp[1]; w2 = wp[2]; w3 = wp[3];
  } else {
    const u16* wp = (const u16*)convwr + (long)c * 4;
    w0 = b2f(wp[0]); w1 = b2f(wp[1]); w2 = b2f(wp[2]); w3 = b2f(wp[3]);
  }
  float acc = w3 * (float)mixed[(long)s * CONV_DIM + c];
  if (s >= 1) acc += w2 * (float)mixed[(long)(s - 1) * CONV_DIM + c];
  if (s >= 2) acc += w1 * (float)mixed[(long)(s - 2) * CONV_DIM + c];
  if (s >= 3) acc += w0 * (float)mixed[(long)(s - 3) * CONV_DIM + c];
  float y = acc * sigmoidf_(acc);  // SiLU
  if (c < 2 * KEY_DIM) {
    float ss = y * y;
    ss += __shfl_xor(ss, 1);  ss += __shfl_xor(ss, 2);  ss += __shfl_xor(ss, 4);
    ss += __shfl_xor(ss, 8);  ss += __shfl_xor(ss, 16); ss += __shfl_xor(ss, 32);
    float scale = rsqrtf(ss + 1e-6f);
    if (c < KEY_DIM) scale *= 0.125f;
    y *= scale;
  }
  if (c < KEY_DIM)            qbuf[(long)s * KEY_DIM + c] = (bf16)y;
  else if (c < 2 * KEY_DIM)   kbuf[(long)s * KEY_DIM + (c - KEY_DIM)] = (bf16)y;
  else                        vbuf[(long)s * VAL_DIM + (c - 2 * KEY_DIM)] = (bf16)y;
}

// ---------------------------------------------------------------- DPP 16-lane sum (fallback scan)
template<int CTRL>
__device__ __forceinline__ float dpp_add(float x) {
  int y = __builtin_amdgcn_update_dpp(0, __float_as_int(x), CTRL, 0xF, 0xF, true);
  return x + __int_as_float(y);
}
__device__ __forceinline__ float dpp_sum16(float x) {
  x = dpp_add<0xB1>(x);   // quad_perm xor1
  x = dpp_add<0x4E>(x);   // quad_perm xor2
  x = dpp_add<0x141>(x);  // row_half_mirror (xor4)
  x = dpp_add<0x140>(x);  // row_mirror (xor8)
  return x;
}

// ---------------------------------------------------------------- fused per-step scan (FALLBACK path only)
__global__ __launch_bounds__(256, 2)
void fused_scan(const bf16* __restrict__ qbuf, const bf16* __restrict__ kbuf,
                const bf16* __restrict__ vbuf, const float* __restrict__ eg,
                const float* __restrict__ bet, bf16* __restrict__ core,
                const bf16* __restrict__ hsb, const bf16* __restrict__ wzb,
                bf16* __restrict__ zbuf, const void* __restrict__ woutr,
                bf16* __restrict__ woutb, const unsigned* __restrict__ flagp,
                int nScan, int nGemm) {
  __shared__ __align__(16) char smem[16384];
  const int t = threadIdx.x;
  const int b = blockIdx.x;

  if (b < nScan) {
    const int h  = b >> 3;
    const int vg = (b & 7) * 16;
    const int g  = t >> 4;
    const int L  = t & 15;
    bf16*  kqs = (bf16*)smem;               // [2][2048] elems
    bf16*  vts = (bf16*)(smem + 8192);      // [2][256] elems
    float* ets = (float*)(smem + 9216);     // [2][16]
    float* bts = (float*)(smem + 9344);     // [2][16]

#define STAGE(buf, s0)                                                          \
    {                                                                           \
      int byte = t * 16;                                                        \
      const bf16* src;                                                          \
      if (byte < 2048) {                                                        \
        int row = byte >> 7, el = (byte & 127) >> 1;                            \
        src = kbuf + (long)((s0) + row) * KEY_DIM + h * DKv + el;               \
      } else {                                                                  \
        int b2 = byte - 2048;                                                   \
        int row = b2 >> 7, el = (b2 & 127) >> 1;                                \
        src = qbuf + (long)((s0) + row) * KEY_DIM + h * DKv + el;               \
      }                                                                         \
      GLDS16(src, smem + (buf) * 4096 + byte);                                  \
      if (t < 32) {                                                             \
        int row = t >> 1, el = (t & 1) * 8;                                     \
        const bf16* vsrc = vbuf + (long)((s0) + row) * VAL_DIM + h * DVv + vg + el; \
        GLDS16(vsrc, smem + 8192 + (buf) * 512 + t * 16);                       \
      }                                                                         \
    }

    float er = 0.f, br = 0.f;
    if (t < 16)      er = eg[(long)t * NH + h];
    else if (t < 32) br = bet[(long)(t - 16) * NH + h];
    STAGE(0, 0);
    if (t < 16)      ets[t] = er;
    else if (t < 32) bts[t - 16] = br;
    __syncthreads();

    float S0 = 0.f, S1 = 0.f, S2 = 0.f, S3 = 0.f;
    for (int tile = 0; tile < 128; ++tile) {
      const int buf = tile & 1, nb = buf ^ 1;
      if (tile < 127) {
        STAGE(nb, (tile + 1) * 16);
        if (t < 16)      er = eg[(long)((tile + 1) * 16 + t) * NH + h];
        else if (t < 32) br = bet[(long)((tile + 1) * 16 + (t - 16)) * NH + h];
      }
      const bf16*  ktb = kqs + buf * 2048;
      const bf16*  qtb = ktb + 1024;
      const bf16*  vtb = vts + buf * 256;
      const float* etb = ets + buf * 16;
      const float* btb = bts + buf * 16;
      const long sbase = (long)tile * 16;

      bf16x4 kR[2], qR[2];
      float  vR[2], eR[2], bR[2];
      kR[0] = *(const bf16x4*)(ktb + 0 * 64 + L * 4);
      qR[0] = *(const bf16x4*)(qtb + 0 * 64 + L * 4);
      vR[0] = (float)vtb[0 * 16 + g];  eR[0] = etb[0];  bR[0] = btb[0];
      kR[1] = *(const bf16x4*)(ktb + 1 * 64 + L * 4);
      qR[1] = *(const bf16x4*)(qtb + 1 * 64 + L * 4);
      vR[1] = (float)vtb[1 * 16 + g];  eR[1] = etb[1];  bR[1] = btb[1];
#pragma unroll
      for (int s = 0; s < 16; ++s) {
        const int sl = s & 1;
        bf16x4 kk = kR[sl], qq = qR[sl];
        float vv = vR[sl], ee = eR[sl], bb = bR[sl];
        if (s < 14) {
          const int s2 = s + 2;
          kR[sl] = *(const bf16x4*)(ktb + s2 * 64 + L * 4);
          qR[sl] = *(const bf16x4*)(qtb + s2 * 64 + L * 4);
          vR[sl] = (float)vtb[s2 * 16 + g];
          eR[sl] = etb[s2];  bR[sl] = btb[s2];
        }
        float ebt = ee * bb, vbt = vv * bb;
        float k0 = (float)kk[0], k1 = (float)kk[1], k2 = (float)kk[2], k3 = (float)kk[3];
        float D0 = S0 * ee, D1 = S1 * ee, D2 = S2 * ee, D3 = S3 * ee;
        float p = (k0 * S0 + k1 * S1) + (k2 * S2 + k3 * S3);
        p = dpp_sum16(p);
        float delta = vbt - ebt * p;
        S0 = fmaf(k0, delta, D0); S1 = fmaf(k1, delta, D1);
        S2 = fmaf(k2, delta, D2); S3 = fmaf(k3, delta, D3);
        float q0 = (float)qq[0], q1 = (float)qq[1], q2 = (float)qq[2], q3 = (float)qq[3];
        float o = (q0 * S0 + q1 * S1) + (q2 * S2 + q3 * S3);
        o = dpp_sum16(o);
        if (L == 0) core[(sbase + s) * VAL_DIM + h * DVv + vg + g] = (bf16)o;
      }
      if (tile < 127) {
        if (t < 16)      ets[nb * 16 + t] = er;
        else if (t < 32) bts[nb * 16 + (t - 16)] = br;
      }
      __syncthreads();
    }
#undef STAGE
  } else if (b < nScan + nGemm) {
    int gb = b - nScan;
    gemm_body_bf16(smem, hsb, wzb, zbuf, VAL_DIM, HIDDEN, gb & 15, gb >> 4, t);
  } else {
    long i = ((long)(b - nScan - nGemm) * 256 + t) * 8;
    if (i < (long)HIDDEN * VAL_DIM) {
      if (*flagp) {
        const f32x4* s = (const f32x4*)((const float*)woutr + i);
        f32x4 a = s[0], c = s[1];
        bf16x8 o;
#pragma unroll
        for (int j = 0; j < 4; ++j) { o[j] = (bf16)a[j]; o[4 + j] = (bf16)c[j]; }
        *(bf16x8*)(woutb + i) = o;
      } else {
        *(bf16x8*)(woutb + i) = *(const bf16x8*)((const bf16*)woutr + i);
      }
    }
  }
}

// ================================================================ CHUNKED DELTA RULE
// chunk length 64, 32 chunks, 16 heads. Per chunk-head (c,h):
//   cum_t = prefix-sum of g; d_t = e^{cum_t}
//   A[t][i] = beta_t e^{cum_t-cum_i} (k_t.k_i), strictly lower
//   [Dloc | W] = (I+A)^{-1} [diag(beta)V | diag(beta*d)K]
//   delta = Dloc - W S0;  S' = e^{cumC} S0 + K'^T delta, K'[i]=e^{cumC-cum_i}k_i
//   O = diag(d) Q S0 + (Minc o Q K^T) delta

// ---------------------------------------------------------------- phase A (scan + woutcvt)
__global__ __launch_bounds__(256, 2)
void chunk_a(const bf16* __restrict__ kbuf, const bf16* __restrict__ vbuf,
             const float* __restrict__ gbuf, const float* __restrict__ betp,
             bf16* __restrict__ dlocT, bf16* __restrict__ whig, bf16* __restrict__ wlog,
             const void* __restrict__ woutr, bf16* __restrict__ woutb,
             const unsigned* __restrict__ flagp) {
  __shared__ __align__(16) char smem[25600];
  const int t = threadIdx.x;
  const int b = blockIdx.x;
  if (b < 512) {
    const int c = b >> 4, h = b & 15;
    bf16*  Ks   = (bf16*)smem;                 // [64][64] 8192 B
    float* At   = (float*)(smem + 8192);       // [64][64] 16384 B, At[i][t] = A[t][i]
    float* cumS = (float*)(smem + 24576);      // 64
    float* bS   = (float*)(smem + 24832);      // 64
    float* dS   = (float*)(smem + 25088);      // 64
    // stage K chunk -> LDS (linear)
#pragma unroll
    for (int it = 0; it < 2; ++it) {
      int byte = (it * 256 + t) * 16;
      int row = byte >> 7, col = (byte & 127) >> 1;
      const bf16* src = kbuf + (long)(c * 64 + row) * KEY_DIM + h * DKv + col;
      GLDS16(src, smem + byte);
    }
    if (t < 64) {  // wave 0: within-chunk prefix sum of log-decay
      float cc = gbuf[(long)(c * 64 + t) * NH + h];
#pragma unroll
      for (int d = 1; d < 64; d <<= 1) { float y = __shfl_up(cc, d); if (t >= d) cc += y; }
      cumS[t] = cc;
      dS[t] = __expf(cc);
      bS[t] = betp[(long)(c * 64 + t) * NH + h];
    }
    {  // zero At (upper+diag must read as 0 in the quad-vectorized substitution)
      f32x4 z = {0.f, 0.f, 0.f, 0.f};
#pragma unroll
      for (int i = 0; i < 4; ++i) ((f32x4*)At)[t * 4 + i] = z;
    }
    __syncthreads();
    // G = K K^T via MFMA; masked+scaled, stored transposed into At
    {
      const int lane = t & 63, wv = t >> 6;
      const int r = lane & 15, q = lane >> 4;
      const bf16x8* Ks8 = (const bf16x8*)Ks;
#pragma unroll
      for (int n = 0; n < 4; ++n) {
        f32x4 acc = {0.f, 0.f, 0.f, 0.f};
#pragma unroll
        for (int kk = 0; kk < 2; ++kk) {
          bf16x8 af  = Ks8[(wv * 16 + r) * 8 + kk * 4 + q];
          bf16x8 bfv = Ks8[(n  * 16 + r) * 8 + kk * 4 + q];
          acc = __builtin_amdgcn_mfma_f32_16x16x32_bf16(af, bfv, acc, 0, 0, 0);
        }
        const int i = n * 16 + r;
#pragma unroll
        for (int rr = 0; rr < 4; ++rr) {
          const int tr = wv * 16 + q * 4 + rr;
          if (i < tr)
            At[i * 64 + tr] = bS[tr] * __expf(cumS[tr] - cumS[i]) * acc[rr];
        }
      }
    }
    __syncthreads();
    // column-parallel forward substitution: x = (I+A)^{-1} r, one column per thread
    if (t < 192) {
      float x[64];
      const long ch = (long)(c * 16 + h);
      if (t < 128) {
#pragma unroll
        for (int s = 0; s < 64; ++s)
          x[s] = bS[s] * (float)vbuf[(long)(c * 64 + s) * VAL_DIM + h * DVv + t];
      } else {
        const int k = t - 128;
#pragma unroll
        for (int s = 0; s < 64; ++s)
          x[s] = bS[s] * dS[s] * (float)Ks[s * 64 + k];
      }
#pragma unroll
      for (int s = 0; s < 64; ++s) {
        const float val = x[s];
        const f32x4* row4 = (const f32x4*)(At + s * 64);
#pragma unroll
        for (int qd = (s >> 2); qd < 16; ++qd) {
          f32x4 a4 = row4[qd];
          x[qd * 4 + 0] = fmaf(-a4[0], val, x[qd * 4 + 0]);
          x[qd * 4 + 1] = fmaf(-a4[1], val, x[qd * 4 + 1]);
          x[qd * 4 + 2] = fmaf(-a4[2], val, x[qd * 4 + 2]);
          x[qd * 4 + 3] = fmaf(-a4[3], val, x[qd * 4 + 3]);
        }
      }
      if (t < 128) {          // Dloc column v=t -> dlocT[v][s] contiguous (bf16x4)
        bf16* dp = dlocT + ch * 8192 + (long)t * 64;
#pragma unroll
        for (int s4 = 0; s4 < 16; ++s4) {
          bf16x4 o;
          o[0] = (bf16)x[s4 * 4 + 0]; o[1] = (bf16)x[s4 * 4 + 1];
          o[2] = (bf16)x[s4 * 4 + 2]; o[3] = (bf16)x[s4 * 4 + 3];
          *(bf16x4*)(dp + s4 * 4) = o;
        }
      } else {                // W column k -> negW hi/lo [t][k] (coalesced per-s across wave)
        const int k = t - 128;
        const long wb = ch * 4096;
#pragma unroll
        for (int s = 0; s < 64; ++s) {
          float v = -x[s];
          bf16 hh = (bf16)v;
          whig[wb + s * 64 + k] = hh;
          wlog[wb + s * 64 + k] = (bf16)(v - (float)hh);
        }
      }
    }
  } else {
    long i = ((long)(b - 512) * 256 + t) * 8;
    if (i < (long)HIDDEN * VAL_DIM) {
      if (*flagp) {
        const f32x4* s = (const f32x4*)((const float*)woutr + i);
        f32x4 a = s[0], cc = s[1];
        bf16x8 o;
#pragma unroll
        for (int j = 0; j < 4; ++j) { o[j] = (bf16)a[j]; o[4 + j] = (bf16)cc[j]; }
        *(bf16x8*)(woutb + i) = o;
      } else {
        *(bf16x8*)(woutb + i) = *(const bf16x8*)((const bf16*)woutr + i);
      }
    }
  }
}

// ---------------------------------------------------------------- phase B: MFMA chunk-serial recurrence
// grid 64 = h*4 + vq (32 v per block). Same as r16.
__global__ __launch_bounds__(256, 1)
void chunk_b(const bf16* __restrict__ qbuf, const bf16* __restrict__ kbuf,
             const float* __restrict__ gbuf, const bf16* __restrict__ dlocT,
             const bf16* __restrict__ whig, const bf16* __restrict__ wlog,
             bf16* __restrict__ dTg, bf16* __restrict__ o1g) {
  __shared__ __align__(16) char smem[114688];
  bf16* Wh  = (bf16*)(smem);             // [2][64][64] swz      16384 B
  bf16* Wl  = (bf16*)(smem + 16384);     // [2][64][64] swz
  bf16* Qs  = (bf16*)(smem + 32768);     // [2][64][64] swz
  bf16* Ks  = (bf16*)(smem + 49152);     // [2][64][64] linear
  bf16* Dls = (bf16*)(smem + 65536);     // [2][32][64] swz (dlocT slice) 8192 B
  bf16* KT  = (bf16*)(smem + 73728);     // [64][64] swz (K^T)   8192 B
  bf16* Shi = (bf16*)(smem + 81920);     // [32][64] swz         4096 B
  bf16* Slo = (bf16*)(smem + 86016);     // [32][64] swz
  bf16* Dth = (bf16*)(smem + 90112);     // [32][64] swz (fS-scaled deltaT hi)
  bf16* Dtl = (bf16*)(smem + 94208);     // [32][64] swz (lo)
  float* fSa = (float*)(smem + 98304);   // [32][64] e^{cumC-cum_t}  8192 B
  float* dSa = (float*)(smem + 106496);  // [32][64] e^{cum_t}

  const int t = threadIdx.x;
  const int h = blockIdx.x >> 2, vq = blockIdx.x & 3;
  const int lane = t & 63, w = t >> 6;
  const int r = lane & 15, q = lane >> 4;
  const int tb = w * 16 + q * 4;

  auto stage = [&](int bb, int cc) {
    const long c16h = (long)(cc * 16 + h);
#pragma unroll
    for (int it = 0; it < 2; ++it) {
      int p = it * 256 + t;
      int row = p >> 3, g = p & 7;
      int sg = ((g ^ (row & 7)) << 3);
      GLDS16(whig + c16h * 4096 + row * 64 + sg, (char*)Wh + bb * 8192 + p * 16);
      GLDS16(wlog + c16h * 4096 + row * 64 + sg, (char*)Wl + bb * 8192 + p * 16);
      GLDS16(qbuf + (long)(cc * 64 + row) * KEY_DIM + h * DKv + sg, (char*)Qs + bb * 8192 + p * 16);
      GLDS16(kbuf + (long)(cc * 64 + row) * KEY_DIM + h * DKv + (g << 3), (char*)Ks + bb * 8192 + p * 16);
    }
    {
      int row = t >> 3, g = t & 7;
      int sg = ((g ^ (row & 7)) << 3);
      GLDS16(dlocT + c16h * 8192 + (long)(vq * 32 + row) * 64 + sg,
             (char*)Dls + bb * 4096 + t * 16);
    }
  };

  {
    float g8[8];
#pragma unroll
    for (int i = 0; i < 8; ++i)
      g8[i] = gbuf[(long)((w * 8 + i) * 64 + lane) * NH + h];
#pragma unroll
    for (int i = 0; i < 8; ++i) {
      float cs = g8[i];
#pragma unroll
      for (int d = 1; d < 64; d <<= 1) { float y = __shfl_up(cs, d); if (lane >= d) cs += y; }
      float tot = __shfl(cs, 63);
      fSa[(w * 8 + i) * 64 + lane] = __expf(tot - cs);
      dSa[(w * 8 + i) * 64 + lane] = __expf(cs);
    }
  }
  {
    f32x4 z = {0.f, 0.f, 0.f, 0.f};
    ((f32x4*)Shi)[t] = z;
    ((f32x4*)Slo)[t] = z;
  }
  stage(0, 0);
  f32x4 Sacc[2] = {};

  const int va = w & 1, kt0 = (w >> 1) * 2;

  for (int c = 0; c < 32; ++c) {
    const int buf = c & 1, nb = buf ^ 1;
    __syncthreads();   // B1: stage[buf] + all LDS writes drained
    if (c < 31) stage(nb, c + 1);
    const bf16* wh = Wh + buf * 4096;
    const bf16* wl = Wl + buf * 4096;
    const bf16* qs = Qs + buf * 4096;
    const bf16* ks = Ks + buf * 4096;
    const bf16* dls = Dls + buf * 2048;
    const float* fS = fSa + c * 64;
    const float* dS = dSa + c * 64;
    const long gch = (long)(c * 16 + h) * 8192 + (long)(vq * 32) * 64;

    if (c < 31) {
      const int k2 = lane;
#pragma unroll
      for (int ii = 0; ii < 16; ++ii) {
        const int i = w * 16 + ii;
        const int pg = (i >> 3) ^ (k2 & 7);
        KT[k2 * 64 + pg * 8 + (i & 7)] = ks[i * 64 + k2];
      }
    }

    float fs4[4], ds4[4];
#pragma unroll
    for (int rr = 0; rr < 4; ++rr) { fs4[rr] = fS[tb + rr]; ds4[rr] = dS[tb + rr]; }

    bf16x8 wahi[2], walo[2], qa[2];
#pragma unroll
    for (int kk = 0; kk < 2; ++kk) {
      const int row = w * 16 + r;
      const int g = (kk * 4 + q) ^ (row & 7);
      wahi[kk] = *(const bf16x8*)(wh + row * 64 + g * 8);
      walo[kk] = *(const bf16x8*)(wl + row * 64 + g * 8);
      qa[kk]   = *(const bf16x8*)(qs + row * 64 + g * 8);
    }
    bf16x8 sh[2][2], sl[2][2];
#pragma unroll
    for (int n = 0; n < 2; ++n)
#pragma unroll
      for (int kk = 0; kk < 2; ++kk) {
        const int vrow = n * 16 + r;
        const int g = (kk * 4 + q) ^ (vrow & 7);
        sh[n][kk] = *(const bf16x8*)(Shi + vrow * 64 + g * 8);
        sl[n][kk] = *(const bf16x8*)(Slo + vrow * 64 + g * 8);
      }
    float dl4[2][4];
#pragma unroll
    for (int n = 0; n < 2; ++n) {
      const int vloc = n * 16 + r;
      const int pg = (tb >> 3) ^ (vloc & 7);
      bf16x4 dv4 = *(const bf16x4*)(dls + vloc * 64 + pg * 8 + (tb & 7));
#pragma unroll
      for (int rr = 0; rr < 4; ++rr) dl4[n][rr] = (float)dv4[rr];
    }

    f32x4 da[2] = {}, oa[2] = {};
#pragma unroll
    for (int n = 0; n < 2; ++n)
#pragma unroll
      for (int kk = 0; kk < 2; ++kk) {
        da[n] = __builtin_amdgcn_mfma_f32_16x16x32_bf16(wahi[kk], sh[n][kk], da[n], 0, 0, 0);
        da[n] = __builtin_amdgcn_mfma_f32_16x16x32_bf16(wahi[kk], sl[n][kk], da[n], 0, 0, 0);
        da[n] = __builtin_amdgcn_mfma_f32_16x16x32_bf16(walo[kk], sh[n][kk], da[n], 0, 0, 0);
        oa[n] = __builtin_amdgcn_mfma_f32_16x16x32_bf16(qa[kk],   sh[n][kk], oa[n], 0, 0, 0);
        oa[n] = __builtin_amdgcn_mfma_f32_16x16x32_bf16(qa[kk],   sl[n][kk], oa[n], 0, 0, 0);
      }

#pragma unroll
    for (int n = 0; n < 2; ++n) {
      const int vloc = n * 16 + r;
      bf16x4 dpk, opk, fhk, flk;
#pragma unroll
      for (int rr = 0; rr < 4; ++rr) {
        float dv = dl4[n][rr] + da[n][rr];
        dpk[rr] = (bf16)dv;
        float p = fs4[rr] * dv;
        bf16 ph = (bf16)p;
        fhk[rr] = ph;
        flk[rr] = (bf16)(p - (float)ph);
        opk[rr] = (bf16)(ds4[rr] * oa[n][rr]);
      }
      *(bf16x4*)(dTg + gch + (long)vloc * 64 + tb) = dpk;
      *(bf16x4*)(o1g + gch + (long)vloc * 64 + tb) = opk;
      const int pg = (tb >> 3) ^ (vloc & 7);
      *(bf16x4*)(Dth + vloc * 64 + pg * 8 + (tb & 7)) = fhk;
      *(bf16x4*)(Dtl + vloc * 64 + pg * 8 + (tb & 7)) = flk;
    }

    // B2: LDS-only barrier; prefetch + global stores stay in flight to next B1.
    asm volatile("s_waitcnt lgkmcnt(0)" ::: "memory");
    __builtin_amdgcn_sched_barrier(0);
    __builtin_amdgcn_s_barrier();
    __builtin_amdgcn_sched_barrier(0);

    if (c < 31) {
      const float dC = dS[63];
      bf16x8 dh[2], dlo2[2], ktf[2][2];
#pragma unroll
      for (int kk = 0; kk < 2; ++kk) {
        const int vrow = va * 16 + r;
        const int g = (kk * 4 + q) ^ (vrow & 7);
        dh[kk]   = *(const bf16x8*)(Dth + vrow * 64 + g * 8);
        dlo2[kk] = *(const bf16x8*)(Dtl + vrow * 64 + g * 8);
      }
#pragma unroll
      for (int m = 0; m < 2; ++m)
#pragma unroll
        for (int kk = 0; kk < 2; ++kk) {
          const int krow = (kt0 + m) * 16 + r;
          const int g = (kk * 4 + q) ^ (krow & 7);
          ktf[m][kk] = *(const bf16x8*)(KT + krow * 64 + g * 8);
        }
#pragma unroll
      for (int m = 0; m < 2; ++m) {
        f32x4 sa;
#pragma unroll
        for (int rr = 0; rr < 4; ++rr) sa[rr] = dC * Sacc[m][rr];
#pragma unroll
        for (int kk = 0; kk < 2; ++kk) {
          sa = __builtin_amdgcn_mfma_f32_16x16x32_bf16(dh[kk],   ktf[m][kk], sa, 0, 0, 0);
          sa = __builtin_amdgcn_mfma_f32_16x16x32_bf16(dlo2[kk], ktf[m][kk], sa, 0, 0, 0);
        }
        Sacc[m] = sa;
        const int k = (kt0 + m) * 16 + r;
#pragma unroll
        for (int rr = 0; rr < 4; ++rr) {
          const int v = va * 16 + q * 4 + rr;
          float s = sa[rr];
          bf16 hh = (bf16)s;
          const int pg = (k >> 3) ^ (v & 7);
          Shi[v * 64 + pg * 8 + (k & 7)] = hh;
          Slo[v * 64 + pg * 8 + (k & 7)] = (bf16)(s - (float)hh);
        }
      }
    }
  }
}

// ---------------------------------------------------------------- phase C: outputs, MFMA
__global__ __launch_bounds__(256, 2)
void chunk_c(const bf16* __restrict__ qbuf, const bf16* __restrict__ kbuf,
             const float* __restrict__ gbuf, const bf16* __restrict__ dTg,
             const bf16* __restrict__ o1g, bf16* __restrict__ core) {
  __shared__ __align__(16) char smem[57600];
  const int t = threadIdx.x;
  const int c = blockIdx.x >> 4, h = blockIdx.x & 15;
  const long c16h = (long)(c * 16 + h);
  bf16* Qs  = (bf16*)smem;
  bf16* Ksl = (bf16*)(smem + 8192);
  bf16* Pl  = (bf16*)(smem + 16384);
  const bf16* dT  = (const bf16*)(smem + 24576);
  const bf16* o1l = (const bf16*)(smem + 40960);
  float* cumS = (float*)(smem + 57344);

#pragma unroll
  for (int it = 0; it < 2; ++it) {
    int byte = (it * 256 + t) * 16;
    int row = byte >> 7, col = (byte & 127) >> 1;
    GLDS16(qbuf + (long)(c * 64 + row) * KEY_DIM + h * DKv + col, smem + byte);
    GLDS16(kbuf + (long)(c * 64 + row) * KEY_DIM + h * DKv + col, smem + 8192 + byte);
  }
#pragma unroll
  for (int it = 0; it < 4; ++it) {
    int byte = (it * 256 + t) * 16;
    GLDS16(dTg + c16h * 8192 + (byte >> 1), smem + 24576 + byte);
    GLDS16(o1g + c16h * 8192 + (byte >> 1), smem + 40960 + byte);
  }
  if (t < 64) {
    float cc = gbuf[(long)(c * 64 + t) * NH + h];
#pragma unroll
    for (int d = 1; d < 64; d <<= 1) { float y = __shfl_up(cc, d); if (t >= d) cc += y; }
    cumS[t] = cc;
  }
  __syncthreads();

  const int lane = t & 63, wv = t >> 6;
  const int r = lane & 15, q = lane >> 4;
  const bf16x8* Qs8 = (const bf16x8*)Qs;
  const bf16x8* Ks8 = (const bf16x8*)Ksl;

#pragma unroll
  for (int n = 0; n < 4; ++n) {
    f32x4 acc = {0.f, 0.f, 0.f, 0.f};
#pragma unroll
    for (int kk = 0; kk < 2; ++kk)
      acc = __builtin_amdgcn_mfma_f32_16x16x32_bf16(
          Qs8[(wv * 16 + r) * 8 + kk * 4 + q], Ks8[(n * 16 + r) * 8 + kk * 4 + q], acc, 0, 0, 0);
    const int i = n * 16 + r;
#pragma unroll
    for (int rr = 0; rr < 4; ++rr) {
      const int tr = wv * 16 + q * 4 + rr;
      Pl[tr * 64 + i] = (i <= tr) ? (bf16)(__expf(cumS[tr] - cumS[i]) * acc[rr]) : (bf16)0.0f;
    }
  }
  __syncthreads();

  {
    const bf16x8* Pl8 = (const bf16x8*)Pl;
    const bf16x8* dT8 = (const bf16x8*)dT;
    bf16x8 pf[2];
#pragma unroll
    for (int kk = 0; kk < 2; ++kk) pf[kk] = Pl8[(wv * 16 + r) * 8 + kk * 4 + q];
#pragma unroll
    for (int n = 0; n < 8; ++n) {
      const int v = n * 16 + r;
      f32x4 acc;
#pragma unroll
      for (int rr = 0; rr < 4; ++rr)
        acc[rr] = (float)o1l[v * 64 + (wv * 16 + q * 4 + rr)];
#pragma unroll
      for (int kk = 0; kk < 2; ++kk)
        acc = __builtin_amdgcn_mfma_f32_16x16x32_bf16(
            pf[kk], dT8[(n * 16 + r) * 8 + kk * 4 + q], acc, 0, 0, 0);
#pragma unroll
      for (int rr = 0; rr < 4; ++rr) {
        const int tr = wv * 16 + q * 4 + rr;
        core[(long)(c * 64 + tr) * VAL_DIM + h * DVv + v] = (bf16)acc[rr];
      }
    }
  }
}

// ---------------------------------------------------------------- RMSNorm + SiLU(z) gate
__global__ __launch_bounds__(256)
void gate_norm(const bf16* __restrict__ core, const bf16* __restrict__ zb,
               const void* __restrict__ normwr, bf16* __restrict__ gated,
               const unsigned* __restrict__ flagp) {
  const bool f32g = (*flagp != 0);
  const int s  = blockIdx.x;
  const int t  = threadIdx.x;
  const int h  = t >> 4;
  const int li = t & 15;
  const long base = (long)s * VAL_DIM + h * DVv + li * 8;
  bf16x8 c8 = *(const bf16x8*)(core + base);
  bf16x8 z8 = *(const bf16x8*)(zb + base);
  float x[8], z[8], nw[8];
  float ss = 0.f;
#pragma unroll
  for (int j = 0; j < 8; ++j) { x[j] = (float)c8[j]; z[j] = (float)z8[j]; ss += x[j] * x[j]; }
  if (f32g) {
    const float* np_ = (const float*)normwr + li * 8;
#pragma unroll
    for (int j = 0; j < 8; ++j) nw[j] = np_[j];
  } else {
    const u16* np_ = (const u16*)normwr + li * 8;
#pragma unroll
    for (int j = 0; j < 8; ++j) nw[j] = b2f(np_[j]);
  }
  ss += __shfl_xor(ss, 1); ss += __shfl_xor(ss, 2);
  ss += __shfl_xor(ss, 4); ss += __shfl_xor(ss, 8);
  float scale = rsqrtf(ss * (1.f / 128.f) + 1e-6f);
#pragma unroll
  for (int j = 0; j < 8; ++j) {
    float y = x[j] * scale * nw[j];
    y *= z[j] * sigmoidf_(z[j]);
    gated[base + j] = (bf16)y;
  }
}

// ---------------------------------------------------------------- launcher
extern "C" void kernel_launch(void* const* d_in, const int* in_sizes, int n_in,
                              void* d_out, int out_size, void* d_ws, size_t ws_size,
                              hipStream_t stream) {
  char* ws = (char*)d_ws;
  const bool big = ws_size >= ((48u << 20) + (512u << 10));

  if (big) {
    // ws: [0,8) hsb -> vbuf -> dTg | [8,24) wcomb(qkv) -> woutb[8,16)+o1g[16,24)
    //     [24,32) wcomb(z) -> whig[24,28)+wlog[28,32) | [32,40) zbuf
    //     [40,44) qbuf [44,48) kbuf -> gated[40,48) | [48M..) eg|beta|g|flag
    // d_out: [0,16) mixed -> core[0,8)+dlocT[8,16) -> final f32 out (16M).
    bf16*  hsb   = (bf16*)ws;
    bf16*  wcomb = (bf16*)(ws + (8u << 20));    // [6144][2048] bf16 = 24 MB
    bf16*  wzpart= (bf16*)(ws + (24u << 20));   // rows 4096-6143 of wcomb
    bf16*  zbuf  = (bf16*)(ws + (32u << 20));
    bf16*  mixed = (bf16*)d_out;                // 2048x4096 bf16 = 16 MB
    bf16*  vbuf  = (bf16*)ws;                   // after gemm (hsb dead)
    bf16*  qbuf  = (bf16*)(ws + (40u << 20));
    bf16*  kbuf  = (bf16*)(ws + (44u << 20));
    bf16*  whig  = (bf16*)(ws + (24u << 20));
    bf16*  wlog  = (bf16*)(ws + (28u << 20));
    bf16*  woutb = (bf16*)(ws + (8u << 20));
    bf16*  dlocp = (bf16*)((char*)d_out + (8u << 20));
    bf16*  dTg   = (bf16*)ws;                   // after chunk_a (vbuf dead)
    bf16*  o1g   = (bf16*)(ws + (16u << 20));
    bf16*  corep = (bf16*)d_out;                // after conv (mixed dead)
    bf16*  gated = (bf16*)(ws + (40u << 20));
    float* egp  = (float*)(ws + (48u << 20));
    float* betp = (float*)(ws + (48u << 20) + (128u << 10));
    float* gbp  = (float*)(ws + (48u << 20) + (256u << 10));
    unsigned* flagp = (unsigned*)(ws + (48u << 20) + (384u << 10));

    detect_dtype<<<1, 64, 0, stream>>>((const u16*)d_in[0], flagp);
    proj_ab<<<SEQ / 8, 256, 0, stream>>>(d_in[0], d_in[2], d_in[3], d_in[6], d_in[7], egp, betp, gbp, flagp);
    cvt_bf16<<<(SEQ * HIDDEN) / 2048, 256, 0, stream>>>(d_in[0], hsb, (long)SEQ * HIDDEN, flagp);
    cvt_bf16<<<(CONV_DIM * HIDDEN) / 2048, 256, 0, stream>>>(d_in[1], wcomb, (long)CONV_DIM * HIDDEN, flagp);
    cvt_bf16<<<(VAL_DIM * HIDDEN) / 2048, 256, 0, stream>>>(d_in[4], wzpart, (long)VAL_DIM * HIDDEN, flagp);
    gemm_qkvz<<<dim3((CONV_DIM + VAL_DIM) / 128, SEQ / 128), 256, 0, stream>>>(hsb, wcomb, mixed, zbuf);
    conv_norm<<<dim3(SEQ, CONV_DIM / 256), 256, 0, stream>>>(mixed, d_in[5], qbuf, kbuf, vbuf, flagp);
    chunk_a<<<512 + 2048, 256, 0, stream>>>(kbuf, vbuf, gbp, betp, dlocp, whig, wlog,
                                            d_in[9], woutb, flagp);
    chunk_b<<<64, 256, 0, stream>>>(qbuf, kbuf, gbp, dlocp, whig, wlog, dTg, o1g);
    chunk_c<<<512, 256, 0, stream>>>(qbuf, kbuf, gbp, dTg, o1g, corep);
    gate_norm<<<SEQ, 256, 0, stream>>>(corep, zbuf, d_in[8], gated, flagp);
    gemm_nt<true><<<dim3(HIDDEN / 128, SEQ / 128), 256, 0, stream>>>(gated, woutb, d_out, HIDDEN, VAL_DIM, flagp, 0, 0);
  } else {
    // Fallback layout (peak 24.26 MiB): r6-style staging GEMMs; per-step scan.
    bf16* mixed = (bf16*)ws;
    bf16* qbuf  = (bf16*)(ws + (16u << 20));
    bf16* kbuf  = (bf16*)(ws + (20u << 20));
    bf16* zbuf  = (bf16*)ws;
    bf16* corep = (bf16*)(ws + (8u << 20));
    bf16* gated = (bf16*)(ws + (16u << 20));
    float* egp  = (float*)(ws + (24u << 20));
    float* betp = (float*)(ws + (24u << 20) + (128u << 10));
    unsigned* flagp = (unsigned*)(ws + (24u << 20) + (256u << 10));
    bf16* vbuf  = (bf16*)d_out;

    detect_dtype<<<1, 64, 0, stream>>>((const u16*)d_in[0], flagp);
    proj_ab<<<SEQ / 8, 256, 0, stream>>>(d_in[0], d_in[2], d_in[3], d_in[6], d_in[7], egp, betp, nullptr, flagp);
    gemm_nt<false><<<dim3(CONV_DIM / 128, SEQ / 128), 256, 0, stream>>>(d_in[0], d_in[1], mixed, CONV_DIM, HIDDEN, flagp, 1, 1);
    conv_norm<<<dim3(SEQ, CONV_DIM / 256), 256, 0, stream>>>(mixed, d_in[5], qbuf, kbuf, vbuf, flagp);
    gemm_nt<false><<<dim3(VAL_DIM / 128, SEQ / 128), 256, 0, stream>>>(d_in[0], d_in[4], zbuf, VAL_DIM, HIDDEN, flagp, 1, 1);
    fused_scan<<<128, 256, 0, stream>>>(qbuf, kbuf, vbuf, egp, betp, corep,
                                        nullptr, nullptr, nullptr, nullptr, nullptr, flagp,
                                        128, 0);
    gate_norm<<<SEQ, 256, 0, stream>>>(corep, zbuf, d_in[8], gated, flagp);
    gemm_nt<true><<<dim3(HIDDEN / 128, SEQ / 128), 256, 0, stream>>>(gated, d_in[9], d_out, HIDDEN, VAL_DIM, flagp, 0, 1);
  }
}

// Round 9
// 426.165 us; speedup vs baseline: 1.1713x; 1.1155x over previous
//
#include <hip/hip_runtime.h>
#include <stdint.h>

// LinearAttention (gated delta rule), S=2048, HID=2048, H=16, DK=64, DV=128, conv K=4.
// r19: REALLY fix proj_ab. r15's version was still transaction-bound (82us; HBM 1.5%,
// VALU 2.5%, Occ 11%): o=t&31 layout makes every weight load instruction scatter
// across 32 rows 8KB apart (32x16B transactions/instr). New structure: wave-per-s-row
// (grid 512 x 4 waves = 8 waves/CU), lane-parallel-K with interleaved partition so
// every x/w load is 64 contiguous 16B lanes (1KB coalesced); x row register-resident
// (loaded once); per-output: 8 coalesced w-loads + 32 FMA + 6-shfl reduce. Finalize
// identical. Only K-summation order changes (prior reorders left absmax unchanged).
// Rest of pipeline identical to r18 (475us).

#define SEQ 2048
#define HIDDEN 2048
#define NH 16
#define DKv 64
#define DVv 128
#define KEY_DIM 1024
#define VAL_DIM 2048
#define CONV_DIM 4096

typedef __bf16 bf16;
typedef unsigned short u16;
typedef __attribute__((ext_vector_type(8))) __bf16 bf16x8;
typedef __attribute__((ext_vector_type(4))) __bf16 bf16x4;
typedef __attribute__((ext_vector_type(4))) float f32x4;

#define AS1 __attribute__((address_space(1)))
#define AS3 __attribute__((address_space(3)))
#define GLDS16(src, dst) __builtin_amdgcn_global_load_lds((AS1 const void*)(src), (AS3 void*)(dst), 16, 0, 0)

__device__ __forceinline__ float b2f(u16 u) {
  union { unsigned int i; float f; } c; c.i = ((unsigned int)u) << 16; return c.f;
}
__device__ __forceinline__ float sigmoidf_(float x) { return 1.0f / (1.0f + __expf(-x)); }

// ---------------------------------------------------------------- dtype detector
__global__ void detect_dtype(const u16* __restrict__ p, unsigned* __restrict__ flag) {
  int lane = threadIdx.x;  // 64 threads
  int cnt = 0;
  for (int w = lane; w < 2048; w += 64) {
    unsigned e = (p[2 * w] >> 7) & 0xFF;
    if (e < 64) cnt++;
  }
  cnt += __shfl_xor(cnt, 1);  cnt += __shfl_xor(cnt, 2);  cnt += __shfl_xor(cnt, 4);
  cnt += __shfl_xor(cnt, 8);  cnt += __shfl_xor(cnt, 16); cnt += __shfl_xor(cnt, 32);
  if (lane == 0) *flag = (cnt > 64) ? 1u : 0u;   // 1 = inputs are f32
}

// ---------------------------------------------------------------- f32 -> bf16 convert
__global__ __launch_bounds__(256)
void cvt_bf16(const void* __restrict__ src, bf16* __restrict__ dst, long n,
              const unsigned* __restrict__ flagp) {
  long i = ((long)blockIdx.x * 256 + threadIdx.x) * 8;
  if (i >= n) return;
  if (*flagp) {
    const f32x4* s = (const f32x4*)((const float*)src + i);
    f32x4 a = s[0], b = s[1];
    bf16x8 o;
#pragma unroll
    for (int j = 0; j < 4; ++j) { o[j] = (bf16)a[j]; o[4 + j] = (bf16)b[j]; }
    *(bf16x8*)(dst + i) = o;
  } else {
    *(bf16x8*)(dst + i) = *(const bf16x8*)((const bf16*)src + i);
  }
}

// ---------------------------------------------------------------- GEMM (NT) standalone, 2-phase dbuf
template<bool F32OUT>
__global__ __launch_bounds__(256, 2)
void gemm_nt(const void* __restrict__ Araw, const void* __restrict__ Braw,
             void* __restrict__ Cv, int N, int K,
             const unsigned* __restrict__ flagp, int useA, int useB) {
  __shared__ __align__(16) bf16 As[2][128 * 32];
  __shared__ __align__(16) bf16 Bs[2][128 * 32];
  const bool f32g = (*flagp != 0);
  const bool fA = useA && f32g;
  const bool fB = useB && f32g;
  const int tid  = threadIdx.x;
  const int lane = tid & 63;
  const int wv   = tid >> 6;
  const int wm   = (wv & 1) << 6;
  const int wn   = (wv >> 1) << 6;
  const long bm  = (long)blockIdx.y * 128;
  const long bn  = (long)blockIdx.x * 128;

  f32x4 acc[4][4] = {};

  auto stage = [&](int bb, int k0) {
#pragma unroll
    for (int it = 0; it < 2; ++it) {
      int e   = (it * 256 + tid) * 8;
      int row = e >> 5;
      int col = e & 31;
      long offA = (bm + row) * (long)K + (k0 + col);
      long offB = (bn + row) * (long)K + (k0 + col);
      if (fA) {
        const float* g = (const float*)Araw + offA;
        f32x4 u0 = *(const f32x4*)g, u1 = *(const f32x4*)(g + 4);
        bf16x8 bv;
#pragma unroll
        for (int j = 0; j < 4; ++j) { bv[j] = (bf16)u0[j]; bv[4 + j] = (bf16)u1[j]; }
        *(bf16x8*)&As[bb][e] = bv;
      } else {
        GLDS16((const bf16*)Araw + offA, &As[bb][e]);
      }
      if (fB) {
        const float* g = (const float*)Braw + offB;
        f32x4 u0 = *(const f32x4*)g, u1 = *(const f32x4*)(g + 4);
        bf16x8 bv;
#pragma unroll
        for (int j = 0; j < 4; ++j) { bv[j] = (bf16)u0[j]; bv[4 + j] = (bf16)u1[j]; }
        *(bf16x8*)&Bs[bb][e] = bv;
      } else {
        GLDS16((const bf16*)Braw + offB, &Bs[bb][e]);
      }
    }
  };

  stage(0, 0);
  __syncthreads();
  int buf = 0;
  const int r = lane & 15, q = lane >> 4;
  const int nk = K >> 5;
  for (int ks = 0; ks < nk; ++ks) {
    if (ks + 1 < nk) stage(buf ^ 1, (ks + 1) * 32);   // prefetch under compute
    const bf16x8* As8 = (const bf16x8*)As[buf];
    const bf16x8* Bs8 = (const bf16x8*)Bs[buf];
    bf16x8 af[4], bfr[4];
#pragma unroll
    for (int i = 0; i < 4; ++i) af[i]  = As8[(wm + i * 16 + r) * 4 + q];
#pragma unroll
    for (int j = 0; j < 4; ++j) bfr[j] = Bs8[(wn + j * 16 + r) * 4 + q];
#pragma unroll
    for (int i = 0; i < 4; ++i)
#pragma unroll
      for (int j = 0; j < 4; ++j)
        acc[i][j] = __builtin_amdgcn_mfma_f32_16x16x32_bf16(af[i], bfr[j], acc[i][j], 0, 0, 0);
    __syncthreads();   // drains prefetch DMA (flew under MFMA) + guards buf reuse
    buf ^= 1;
  }

#pragma unroll
  for (int i = 0; i < 4; ++i)
#pragma unroll
    for (int j = 0; j < 4; ++j) {
      long row = bm + wm + i * 16 + q * 4;
      long col = bn + wn + j * 16 + r;
#pragma unroll
      for (int rr = 0; rr < 4; ++rr) {
        if constexpr (F32OUT) ((float*)Cv)[(row + rr) * N + col] = acc[i][j][rr];
        else                  ((bf16*)Cv)[(row + rr) * N + col] = (bf16)acc[i][j][rr];
      }
    }
}

// ---------------------------------------------------------------- combined QKV+Z GEMM (bf16, dbuf, split epilogue)
// A = hsb [2048][2048], B = wcomb [6144][2048] (rows 0-4095 = wqkv, 4096-6143 = wz).
// C cols 0-4095 -> mixed (stride 4096), cols 4096-6143 -> zbuf (stride 2048).
__global__ __launch_bounds__(256, 2)
void gemm_qkvz(const bf16* __restrict__ A, const bf16* __restrict__ B,
               bf16* __restrict__ Cmixed, bf16* __restrict__ Cz) {
  __shared__ __align__(16) bf16 As[2][128 * 32];
  __shared__ __align__(16) bf16 Bs[2][128 * 32];
  const int tid  = threadIdx.x;
  const int lane = tid & 63;
  const int wv   = tid >> 6;
  const int wm   = (wv & 1) << 6;
  const int wn   = (wv >> 1) << 6;
  const long bm  = (long)blockIdx.y * 128;
  const long bn  = (long)blockIdx.x * 128;
  const int K = HIDDEN;

  f32x4 acc[4][4] = {};

  auto stage = [&](int bb, int k0) {
#pragma unroll
    for (int it = 0; it < 2; ++it) {
      int e = (it * 256 + tid) * 8;
      int row = e >> 5, col = e & 31;
      GLDS16(A + (bm + row) * (long)K + k0 + col, &As[bb][e]);
      GLDS16(B + (bn + row) * (long)K + k0 + col, &Bs[bb][e]);
    }
  };

  stage(0, 0);
  __syncthreads();
  int buf = 0;
  const int r = lane & 15, q = lane >> 4;
  const int nk = K >> 5;
  for (int ks = 0; ks < nk; ++ks) {
    if (ks + 1 < nk) stage(buf ^ 1, (ks + 1) * 32);
    const bf16x8* As8 = (const bf16x8*)As[buf];
    const bf16x8* Bs8 = (const bf16x8*)Bs[buf];
    bf16x8 af[4], bfr[4];
#pragma unroll
    for (int i = 0; i < 4; ++i) af[i]  = As8[(wm + i * 16 + r) * 4 + q];
#pragma unroll
    for (int j = 0; j < 4; ++j) bfr[j] = Bs8[(wn + j * 16 + r) * 4 + q];
#pragma unroll
    for (int i = 0; i < 4; ++i)
#pragma unroll
      for (int j = 0; j < 4; ++j)
        acc[i][j] = __builtin_amdgcn_mfma_f32_16x16x32_bf16(af[i], bfr[j], acc[i][j], 0, 0, 0);
    __syncthreads();
    buf ^= 1;
  }

  const bool isz = (bn >= 4096);
  bf16* Cp = isz ? Cz : Cmixed;
  const long cstride = isz ? 2048 : 4096;
  const long cb = (isz ? (bn - 4096) : bn) + wn;
#pragma unroll
  for (int i = 0; i < 4; ++i)
#pragma unroll
    for (int j = 0; j < 4; ++j) {
      long row = bm + wm + i * 16 + q * 4;
      long col = cb + j * 16 + r;
#pragma unroll
      for (int rr = 0; rr < 4; ++rr)
        Cp[(row + rr) * cstride + col] = (bf16)acc[i][j][rr];
    }
}

// ---------------------------------------------------------------- GEMM body (bf16-only, fallback fused)
__device__ void gemm_body_bf16(char* smemc, const bf16* __restrict__ A,
                               const bf16* __restrict__ B, bf16* __restrict__ C,
                               int N, int K, int bx, int by, int tid) {
  bf16* As = (bf16*)smemc;             // 8 KiB
  bf16* Bs = (bf16*)(smemc + 8192);    // 8 KiB
  const int lane = tid & 63;
  const int wv = tid >> 6, wm = (wv & 1) << 6, wn = (wv >> 1) << 6;
  const long bm = (long)by * 128, bn = (long)bx * 128;
  f32x4 acc[4][4] = {};
  for (int k0 = 0; k0 < K; k0 += 32) {
#pragma unroll
    for (int it = 0; it < 2; ++it) {
      int e = (it * 256 + tid) * 8;
      int row = e >> 5, col = e & 31;
      const bf16* gA = A + (bm + row) * (long)K + k0 + col;
      const bf16* gB = B + (bn + row) * (long)K + k0 + col;
      GLDS16(gA, &As[e]);
      GLDS16(gB, &Bs[e]);
    }
    __syncthreads();
    const bf16x8* As8 = (const bf16x8*)As;
    const bf16x8* Bs8 = (const bf16x8*)Bs;
    const int r = lane & 15, q = lane >> 4;
    bf16x8 af[4], bfr[4];
#pragma unroll
    for (int i = 0; i < 4; ++i) af[i]  = As8[(wm + i * 16 + r) * 4 + q];
#pragma unroll
    for (int j = 0; j < 4; ++j) bfr[j] = Bs8[(wn + j * 16 + r) * 4 + q];
#pragma unroll
    for (int i = 0; i < 4; ++i)
#pragma unroll
      for (int j = 0; j < 4; ++j)
        acc[i][j] = __builtin_amdgcn_mfma_f32_16x16x32_bf16(af[i], bfr[j], acc[i][j], 0, 0, 0);
    __syncthreads();
  }
  const int r = lane & 15, q = lane >> 4;
#pragma unroll
  for (int i = 0; i < 4; ++i)
#pragma unroll
    for (int j = 0; j < 4; ++j) {
      long row = bm + wm + i * 16 + q * 4;
      long col = bn + wn + j * 16 + r;
#pragma unroll
      for (int rr = 0; rr < 4; ++rr)
        C[(row + rr) * (long)N + col] = (bf16)acc[i][j][rr];
    }
}

// ---------------------------------------------------------------- a/b proj -> exp(g), g, beta
// r19: wave-per-s-row, lane-parallel-K. Grid SEQ/4, 4 waves/block, 8 waves/CU.
// Interleaved K partition: lane covers k in {i*256 + lane*4 .. +3} -> every load
// instruction is 64 contiguous 16B lanes (1KB coalesced). x row register-resident.
__global__ __launch_bounds__(256)
void proj_ab(const void* __restrict__ hsr, const void* __restrict__ War,
             const void* __restrict__ Wbr, const void* __restrict__ A_logr,
             const void* __restrict__ dtbr,
             float* __restrict__ eg, float* __restrict__ bet,
             float* __restrict__ gb,
             const unsigned* __restrict__ flagp) {
  const bool f32g = (*flagp != 0);
  const int t    = threadIdx.x;
  const int w    = t >> 6;
  const int lane = t & 63;
  const long s   = (long)blockIdx.x * 4 + w;
  __shared__ float red[4][32];

  float xr[32];
  if (f32g) {
    const f32x4* x4 = (const f32x4*)((const float*)hsr + s * HIDDEN);
#pragma unroll
    for (int i = 0; i < 8; ++i) {
      f32x4 v = x4[i * 64 + lane];
#pragma unroll
      for (int j = 0; j < 4; ++j) xr[i * 4 + j] = v[j];
    }
  } else {
    const bf16x8* x8 = (const bf16x8*)((const bf16*)hsr + s * HIDDEN);
#pragma unroll
    for (int i = 0; i < 4; ++i) {
      bf16x8 v = x8[i * 64 + lane];
#pragma unroll
      for (int j = 0; j < 8; ++j) xr[i * 8 + j] = (float)v[j];
    }
  }

#pragma unroll 1
  for (int o = 0; o < 32; ++o) {
    const int h = o & 15;
    float acc = 0.f;
    if (f32g) {
      const f32x4* w4 = (const f32x4*)((const float*)((o < 16) ? War : Wbr) + (long)h * HIDDEN);
#pragma unroll
      for (int i = 0; i < 8; ++i) {
        f32x4 v = w4[i * 64 + lane];
#pragma unroll
        for (int j = 0; j < 4; ++j) acc = fmaf(xr[i * 4 + j], v[j], acc);
      }
    } else {
      const bf16x8* w8 = (const bf16x8*)((const bf16*)((o < 16) ? War : Wbr) + (long)h * HIDDEN);
#pragma unroll
      for (int i = 0; i < 4; ++i) {
        bf16x8 v = w8[i * 64 + lane];
#pragma unroll
        for (int j = 0; j < 8; ++j) acc = fmaf(xr[i * 8 + j], (float)v[j], acc);
      }
    }
    acc += __shfl_xor(acc, 1);  acc += __shfl_xor(acc, 2);  acc += __shfl_xor(acc, 4);
    acc += __shfl_xor(acc, 8);  acc += __shfl_xor(acc, 16); acc += __shfl_xor(acc, 32);
    if (lane == 0) red[w][o] = acc;
  }
  // same-wave LDS write->read: no barrier needed (compiler inserts lgkmcnt)
  if (lane < 32) {
    const int o = lane;
    const int h = o & 15;
    const float a = red[w][o];
    if (o < 16) {
      float alog = f32g ? ((const float*)A_logr)[h] : b2f(((const u16*)A_logr)[h]);
      float dtb  = f32g ? ((const float*)dtbr)[h]   : b2f(((const u16*)dtbr)[h]);
      float xx = a + dtb;
      float sp = fmaxf(xx, 0.f) + log1pf(__expf(-fabsf(xx)));   // stable softplus
      float gg = -__expf(alog) * sp;                             // log-decay
      if (gb) gb[s * NH + h] = gg;
      eg[s * NH + h] = __expf(gg);
    } else {
      bet[s * NH + h] = sigmoidf_(a);
    }
  }
}

// ---------------------------------------------------------------- conv + SiLU + l2norm
__global__ __launch_bounds__(256)
void conv_norm(const bf16* __restrict__ mixed, const void* __restrict__ convwr,
               bf16* __restrict__ qbuf, bf16* __restrict__ kbuf, bf16* __restrict__ vbuf,
               const unsigned* __restrict__ flagp) {
  const bool f32g = (*flagp != 0);
  const int s = blockIdx.x;
  const int c = blockIdx.y * 256 + threadIdx.x;
  float w0, w1, w2, w3;
  if (f32g) {
    const float* wp = (const float*)convwr + (long)c * 4;
    w0 = wp[0]; w1 = wp[1]; w2 = wp[2]; w3 = wp[3];
  } else {
    const u16* wp = (const u16*)convwr + (long)c * 4;
    w0 = b2f(wp[0]); w1 = b2f(wp[1]); w2 = b2f(wp[2]); w3 = b2f(wp[3]);
  }
  float acc = w3 * (float)mixed[(long)s * CONV_DIM + c];
  if (s >= 1) acc += w2 * (float)mixed[(long)(s - 1) * CONV_DIM + c];
  if (s >= 2) acc += w1 * (float)mixed[(long)(s - 2) * CONV_DIM + c];
  if (s >= 3) acc += w0 * (float)mixed[(long)(s - 3) * CONV_DIM + c];
  float y = acc * sigmoidf_(acc);  // SiLU
  if (c < 2 * KEY_DIM) {
    float ss = y * y;
    ss += __shfl_xor(ss, 1);  ss += __shfl_xor(ss, 2);  ss += __shfl_xor(ss, 4);
    ss += __shfl_xor(ss, 8);  ss += __shfl_xor(ss, 16); ss += __shfl_xor(ss, 32);
    float scale = rsqrtf(ss + 1e-6f);
    if (c < KEY_DIM) scale *= 0.125f;
    y *= scale;
  }
  if (c < KEY_DIM)            qbuf[(long)s * KEY_DIM + c] = (bf16)y;
  else if (c < 2 * KEY_DIM)   kbuf[(long)s * KEY_DIM + (c - KEY_DIM)] = (bf16)y;
  else                        vbuf[(long)s * VAL_DIM + (c - 2 * KEY_DIM)] = (bf16)y;
}

// ---------------------------------------------------------------- DPP 16-lane sum (fallback scan)
template<int CTRL>
__device__ __forceinline__ float dpp_add(float x) {
  int y = __builtin_amdgcn_update_dpp(0, __float_as_int(x), CTRL, 0xF, 0xF, true);
  return x + __int_as_float(y);
}
__device__ __forceinline__ float dpp_sum16(float x) {
  x = dpp_add<0xB1>(x);   // quad_perm xor1
  x = dpp_add<0x4E>(x);   // quad_perm xor2
  x = dpp_add<0x141>(x);  // row_half_mirror (xor4)
  x = dpp_add<0x140>(x);  // row_mirror (xor8)
  return x;
}

// ---------------------------------------------------------------- fused per-step scan (FALLBACK path only)
__global__ __launch_bounds__(256, 2)
void fused_scan(const bf16* __restrict__ qbuf, const bf16* __restrict__ kbuf,
                const bf16* __restrict__ vbuf, const float* __restrict__ eg,
                const float* __restrict__ bet, bf16* __restrict__ core,
                const bf16* __restrict__ hsb, const bf16* __restrict__ wzb,
                bf16* __restrict__ zbuf, const void* __restrict__ woutr,
                bf16* __restrict__ woutb, const unsigned* __restrict__ flagp,
                int nScan, int nGemm) {
  __shared__ __align__(16) char smem[16384];
  const int t = threadIdx.x;
  const int b = blockIdx.x;

  if (b < nScan) {
    const int h  = b >> 3;
    const int vg = (b & 7) * 16;
    const int g  = t >> 4;
    const int L  = t & 15;
    bf16*  kqs = (bf16*)smem;               // [2][2048] elems
    bf16*  vts = (bf16*)(smem + 8192);      // [2][256] elems
    float* ets = (float*)(smem + 9216);     // [2][16]
    float* bts = (float*)(smem + 9344);     // [2][16]

#define STAGE(buf, s0)                                                          \
    {                                                                           \
      int byte = t * 16;                                                        \
      const bf16* src;                                                          \
      if (byte < 2048) {                                                        \
        int row = byte >> 7, el = (byte & 127) >> 1;                            \
        src = kbuf + (long)((s0) + row) * KEY_DIM + h * DKv + el;               \
      } else {                                                                  \
        int b2 = byte - 2048;                                                   \
        int row = b2 >> 7, el = (b2 & 127) >> 1;                                \
        src = qbuf + (long)((s0) + row) * KEY_DIM + h * DKv + el;               \
      }                                                                         \
      GLDS16(src, smem + (buf) * 4096 + byte);                                  \
      if (t < 32) {                                                             \
        int row = t >> 1, el = (t & 1) * 8;                                     \
        const bf16* vsrc = vbuf + (long)((s0) + row) * VAL_DIM + h * DVv + vg + el; \
        GLDS16(vsrc, smem + 8192 + (buf) * 512 + t * 16);                       \
      }                                                                         \
    }

    float er = 0.f, br = 0.f;
    if (t < 16)      er = eg[(long)t * NH + h];
    else if (t < 32) br = bet[(long)(t - 16) * NH + h];
    STAGE(0, 0);
    if (t < 16)      ets[t] = er;
    else if (t < 32) bts[t - 16] = br;
    __syncthreads();

    float S0 = 0.f, S1 = 0.f, S2 = 0.f, S3 = 0.f;
    for (int tile = 0; tile < 128; ++tile) {
      const int buf = tile & 1, nb = buf ^ 1;
      if (tile < 127) {
        STAGE(nb, (tile + 1) * 16);
        if (t < 16)      er = eg[(long)((tile + 1) * 16 + t) * NH + h];
        else if (t < 32) br = bet[(long)((tile + 1) * 16 + (t - 16)) * NH + h];
      }
      const bf16*  ktb = kqs + buf * 2048;
      const bf16*  qtb = ktb + 1024;
      const bf16*  vtb = vts + buf * 256;
      const float* etb = ets + buf * 16;
      const float* btb = bts + buf * 16;
      const long sbase = (long)tile * 16;

      bf16x4 kR[2], qR[2];
      float  vR[2], eR[2], bR[2];
      kR[0] = *(const bf16x4*)(ktb + 0 * 64 + L * 4);
      qR[0] = *(const bf16x4*)(qtb + 0 * 64 + L * 4);
      vR[0] = (float)vtb[0 * 16 + g];  eR[0] = etb[0];  bR[0] = btb[0];
      kR[1] = *(const bf16x4*)(ktb + 1 * 64 + L * 4);
      qR[1] = *(const bf16x4*)(qtb + 1 * 64 + L * 4);
      vR[1] = (float)vtb[1 * 16 + g];  eR[1] = etb[1];  bR[1] = btb[1];
#pragma unroll
      for (int s = 0; s < 16; ++s) {
        const int sl = s & 1;
        bf16x4 kk = kR[sl], qq = qR[sl];
        float vv = vR[sl], ee = eR[sl], bb = bR[sl];
        if (s < 14) {
          const int s2 = s + 2;
          kR[sl] = *(const bf16x4*)(ktb + s2 * 64 + L * 4);
          qR[sl] = *(const bf16x4*)(qtb + s2 * 64 + L * 4);
          vR[sl] = (float)vtb[s2 * 16 + g];
          eR[sl] = etb[s2];  bR[sl] = btb[s2];
        }
        float ebt = ee * bb, vbt = vv * bb;
        float k0 = (float)kk[0], k1 = (float)kk[1], k2 = (float)kk[2], k3 = (float)kk[3];
        float D0 = S0 * ee, D1 = S1 * ee, D2 = S2 * ee, D3 = S3 * ee;
        float p = (k0 * S0 + k1 * S1) + (k2 * S2 + k3 * S3);
        p = dpp_sum16(p);
        float delta = vbt - ebt * p;
        S0 = fmaf(k0, delta, D0); S1 = fmaf(k1, delta, D1);
        S2 = fmaf(k2, delta, D2); S3 = fmaf(k3, delta, D3);
        float q0 = (float)qq[0], q1 = (float)qq[1], q2 = (float)qq[2], q3 = (float)qq[3];
        float o = (q0 * S0 + q1 * S1) + (q2 * S2 + q3 * S3);
        o = dpp_sum16(o);
        if (L == 0) core[(sbase + s) * VAL_DIM + h * DVv + vg + g] = (bf16)o;
      }
      if (tile < 127) {
        if (t < 16)      ets[nb * 16 + t] = er;
        else if (t < 32) bts[nb * 16 + (t - 16)] = br;
      }
      __syncthreads();
    }
#undef STAGE
  } else if (b < nScan + nGemm) {
    int gb = b - nScan;
    gemm_body_bf16(smem, hsb, wzb, zbuf, VAL_DIM, HIDDEN, gb & 15, gb >> 4, t);
  } else {
    long i = ((long)(b - nScan - nGemm) * 256 + t) * 8;
    if (i < (long)HIDDEN * VAL_DIM) {
      if (*flagp) {
        const f32x4* s = (const f32x4*)((const float*)woutr + i);
        f32x4 a = s[0], c = s[1];
        bf16x8 o;
#pragma unroll
        for (int j = 0; j < 4; ++j) { o[j] = (bf16)a[j]; o[4 + j] = (bf16)c[j]; }
        *(bf16x8*)(woutb + i) = o;
      } else {
        *(bf16x8*)(woutb + i) = *(const bf16x8*)((const bf16*)woutr + i);
      }
    }
  }
}

// ================================================================ CHUNKED DELTA RULE
// chunk length 64, 32 chunks, 16 heads. Per chunk-head (c,h):
//   cum_t = prefix-sum of g; d_t = e^{cum_t}
//   A[t][i] = beta_t e^{cum_t-cum_i} (k_t.k_i), strictly lower
//   [Dloc | W] = (I+A)^{-1} [diag(beta)V | diag(beta*d)K]
//   delta = Dloc - W S0;  S' = e^{cumC} S0 + K'^T delta, K'[i]=e^{cumC-cum_i}k_i
//   O = diag(d) Q S0 + (Minc o Q K^T) delta

// ---------------------------------------------------------------- phase A (scan + woutcvt)
__global__ __launch_bounds__(256, 2)
void chunk_a(const bf16* __restrict__ kbuf, const bf16* __restrict__ vbuf,
             const float* __restrict__ gbuf, const float* __restrict__ betp,
             bf16* __restrict__ dlocT, bf16* __restrict__ whig, bf16* __restrict__ wlog,
             const void* __restrict__ woutr, bf16* __restrict__ woutb,
             const unsigned* __restrict__ flagp) {
  __shared__ __align__(16) char smem[25600];
  const int t = threadIdx.x;
  const int b = blockIdx.x;
  if (b < 512) {
    const int c = b >> 4, h = b & 15;
    bf16*  Ks   = (bf16*)smem;                 // [64][64] 8192 B
    float* At   = (float*)(smem + 8192);       // [64][64] 16384 B, At[i][t] = A[t][i]
    float* cumS = (float*)(smem + 24576);      // 64
    float* bS   = (float*)(smem + 24832);      // 64
    float* dS   = (float*)(smem + 25088);      // 64
    // stage K chunk -> LDS (linear)
#pragma unroll
    for (int it = 0; it < 2; ++it) {
      int byte = (it * 256 + t) * 16;
      int row = byte >> 7, col = (byte & 127) >> 1;
      const bf16* src = kbuf + (long)(c * 64 + row) * KEY_DIM + h * DKv + col;
      GLDS16(src, smem + byte);
    }
    if (t < 64) {  // wave 0: within-chunk prefix sum of log-decay
      float cc = gbuf[(long)(c * 64 + t) * NH + h];
#pragma unroll
      for (int d = 1; d < 64; d <<= 1) { float y = __shfl_up(cc, d); if (t >= d) cc += y; }
      cumS[t] = cc;
      dS[t] = __expf(cc);
      bS[t] = betp[(long)(c * 64 + t) * NH + h];
    }
    {  // zero At (upper+diag must read as 0 in the quad-vectorized substitution)
      f32x4 z = {0.f, 0.f, 0.f, 0.f};
#pragma unroll
      for (int i = 0; i < 4; ++i) ((f32x4*)At)[t * 4 + i] = z;
    }
    __syncthreads();
    // G = K K^T via MFMA; masked+scaled, stored transposed into At
    {
      const int lane = t & 63, wv = t >> 6;
      const int r = lane & 15, q = lane >> 4;
      const bf16x8* Ks8 = (const bf16x8*)Ks;
#pragma unroll
      for (int n = 0; n < 4; ++n) {
        f32x4 acc = {0.f, 0.f, 0.f, 0.f};
#pragma unroll
        for (int kk = 0; kk < 2; ++kk) {
          bf16x8 af  = Ks8[(wv * 16 + r) * 8 + kk * 4 + q];
          bf16x8 bfv = Ks8[(n  * 16 + r) * 8 + kk * 4 + q];
          acc = __builtin_amdgcn_mfma_f32_16x16x32_bf16(af, bfv, acc, 0, 0, 0);
        }
        const int i = n * 16 + r;
#pragma unroll
        for (int rr = 0; rr < 4; ++rr) {
          const int tr = wv * 16 + q * 4 + rr;
          if (i < tr)
            At[i * 64 + tr] = bS[tr] * __expf(cumS[tr] - cumS[i]) * acc[rr];
        }
      }
    }
    __syncthreads();
    // column-parallel forward substitution: x = (I+A)^{-1} r, one column per thread
    if (t < 192) {
      float x[64];
      const long ch = (long)(c * 16 + h);
      if (t < 128) {
#pragma unroll
        for (int s = 0; s < 64; ++s)
          x[s] = bS[s] * (float)vbuf[(long)(c * 64 + s) * VAL_DIM + h * DVv + t];
      } else {
        const int k = t - 128;
#pragma unroll
        for (int s = 0; s < 64; ++s)
          x[s] = bS[s] * dS[s] * (float)Ks[s * 64 + k];
      }
#pragma unroll
      for (int s = 0; s < 64; ++s) {
        const float val = x[s];
        const f32x4* row4 = (const f32x4*)(At + s * 64);
#pragma unroll
        for (int qd = (s >> 2); qd < 16; ++qd) {
          f32x4 a4 = row4[qd];
          x[qd * 4 + 0] = fmaf(-a4[0], val, x[qd * 4 + 0]);
          x[qd * 4 + 1] = fmaf(-a4[1], val, x[qd * 4 + 1]);
          x[qd * 4 + 2] = fmaf(-a4[2], val, x[qd * 4 + 2]);
          x[qd * 4 + 3] = fmaf(-a4[3], val, x[qd * 4 + 3]);
        }
      }
      if (t < 128) {          // Dloc column v=t -> dlocT[v][s] contiguous (bf16x4)
        bf16* dp = dlocT + ch * 8192 + (long)t * 64;
#pragma unroll
        for (int s4 = 0; s4 < 16; ++s4) {
          bf16x4 o;
          o[0] = (bf16)x[s4 * 4 + 0]; o[1] = (bf16)x[s4 * 4 + 1];
          o[2] = (bf16)x[s4 * 4 + 2]; o[3] = (bf16)x[s4 * 4 + 3];
          *(bf16x4*)(dp + s4 * 4) = o;
        }
      } else {                // W column k -> negW hi/lo [t][k] (coalesced per-s across wave)
        const int k = t - 128;
        const long wb = ch * 4096;
#pragma unroll
        for (int s = 0; s < 64; ++s) {
          float v = -x[s];
          bf16 hh = (bf16)v;
          whig[wb + s * 64 + k] = hh;
          wlog[wb + s * 64 + k] = (bf16)(v - (float)hh);
        }
      }
    }
  } else {
    long i = ((long)(b - 512) * 256 + t) * 8;
    if (i < (long)HIDDEN * VAL_DIM) {
      if (*flagp) {
        const f32x4* s = (const f32x4*)((const float*)woutr + i);
        f32x4 a = s[0], cc = s[1];
        bf16x8 o;
#pragma unroll
        for (int j = 0; j < 4; ++j) { o[j] = (bf16)a[j]; o[4 + j] = (bf16)cc[j]; }
        *(bf16x8*)(woutb + i) = o;
      } else {
        *(bf16x8*)(woutb + i) = *(const bf16x8*)((const bf16*)woutr + i);
      }
    }
  }
}

// ---------------------------------------------------------------- phase B: MFMA chunk-serial recurrence
// grid 64 = h*4 + vq (32 v per block). Same as r16.
__global__ __launch_bounds__(256, 1)
void chunk_b(const bf16* __restrict__ qbuf, const bf16* __restrict__ kbuf,
             const float* __restrict__ gbuf, const bf16* __restrict__ dlocT,
             const bf16* __restrict__ whig, const bf16* __restrict__ wlog,
             bf16* __restrict__ dTg, bf16* __restrict__ o1g) {
  __shared__ __align__(16) char smem[114688];
  bf16* Wh  = (bf16*)(smem);             // [2][64][64] swz      16384 B
  bf16* Wl  = (bf16*)(smem + 16384);     // [2][64][64] swz
  bf16* Qs  = (bf16*)(smem + 32768);     // [2][64][64] swz
  bf16* Ks  = (bf16*)(smem + 49152);     // [2][64][64] linear
  bf16* Dls = (bf16*)(smem + 65536);     // [2][32][64] swz (dlocT slice) 8192 B
  bf16* KT  = (bf16*)(smem + 73728);     // [64][64] swz (K^T)   8192 B
  bf16* Shi = (bf16*)(smem + 81920);     // [32][64] swz         4096 B
  bf16* Slo = (bf16*)(smem + 86016);     // [32][64] swz
  bf16* Dth = (bf16*)(smem + 90112);     // [32][64] swz (fS-scaled deltaT hi)
  bf16* Dtl = (bf16*)(smem + 94208);     // [32][64] swz (lo)
  float* fSa = (float*)(smem + 98304);   // [32][64] e^{cumC-cum_t}  8192 B
  float* dSa = (float*)(smem + 106496);  // [32][64] e^{cum_t}

  const int t = threadIdx.x;
  const int h = blockIdx.x >> 2, vq = blockIdx.x & 3;
  const int lane = t & 63, w = t >> 6;
  const int r = lane & 15, q = lane >> 4;
  const int tb = w * 16 + q * 4;

  auto stage = [&](int bb, int cc) {
    const long c16h = (long)(cc * 16 + h);
#pragma unroll
    for (int it = 0; it < 2; ++it) {
      int p = it * 256 + t;
      int row = p >> 3, g = p & 7;
      int sg = ((g ^ (row & 7)) << 3);
      GLDS16(whig + c16h * 4096 + row * 64 + sg, (char*)Wh + bb * 8192 + p * 16);
      GLDS16(wlog + c16h * 4096 + row * 64 + sg, (char*)Wl + bb * 8192 + p * 16);
      GLDS16(qbuf + (long)(cc * 64 + row) * KEY_DIM + h * DKv + sg, (char*)Qs + bb * 8192 + p * 16);
      GLDS16(kbuf + (long)(cc * 64 + row) * KEY_DIM + h * DKv + (g << 3), (char*)Ks + bb * 8192 + p * 16);
    }
    {
      int row = t >> 3, g = t & 7;
      int sg = ((g ^ (row & 7)) << 3);
      GLDS16(dlocT + c16h * 8192 + (long)(vq * 32 + row) * 64 + sg,
             (char*)Dls + bb * 4096 + t * 16);
    }
  };

  {
    float g8[8];
#pragma unroll
    for (int i = 0; i < 8; ++i)
      g8[i] = gbuf[(long)((w * 8 + i) * 64 + lane) * NH + h];
#pragma unroll
    for (int i = 0; i < 8; ++i) {
      float cs = g8[i];
#pragma unroll
      for (int d = 1; d < 64; d <<= 1) { float y = __shfl_up(cs, d); if (lane >= d) cs += y; }
      float tot = __shfl(cs, 63);
      fSa[(w * 8 + i) * 64 + lane] = __expf(tot - cs);
      dSa[(w * 8 + i) * 64 + lane] = __expf(cs);
    }
  }
  {
    f32x4 z = {0.f, 0.f, 0.f, 0.f};
    ((f32x4*)Shi)[t] = z;
    ((f32x4*)Slo)[t] = z;
  }
  stage(0, 0);
  f32x4 Sacc[2] = {};

  const int va = w & 1, kt0 = (w >> 1) * 2;

  for (int c = 0; c < 32; ++c) {
    const int buf = c & 1, nb = buf ^ 1;
    __syncthreads();   // B1: stage[buf] + all LDS writes drained
    if (c < 31) stage(nb, c + 1);
    const bf16* wh = Wh + buf * 4096;
    const bf16* wl = Wl + buf * 4096;
    const bf16* qs = Qs + buf * 4096;
    const bf16* ks = Ks + buf * 4096;
    const bf16* dls = Dls + buf * 2048;
    const float* fS = fSa + c * 64;
    const float* dS = dSa + c * 64;
    const long gch = (long)(c * 16 + h) * 8192 + (long)(vq * 32) * 64;

    if (c < 31) {
      const int k2 = lane;
#pragma unroll
      for (int ii = 0; ii < 16; ++ii) {
        const int i = w * 16 + ii;
        const int pg = (i >> 3) ^ (k2 & 7);
        KT[k2 * 64 + pg * 8 + (i & 7)] = ks[i * 64 + k2];
      }
    }

    float fs4[4], ds4[4];
#pragma unroll
    for (int rr = 0; rr < 4; ++rr) { fs4[rr] = fS[tb + rr]; ds4[rr] = dS[tb + rr]; }

    bf16x8 wahi[2], walo[2], qa[2];
#pragma unroll
    for (int kk = 0; kk < 2; ++kk) {
      const int row = w * 16 + r;
      const int g = (kk * 4 + q) ^ (row & 7);
      wahi[kk] = *(const bf16x8*)(wh + row * 64 + g * 8);
      walo[kk] = *(const bf16x8*)(wl + row * 64 + g * 8);
      qa[kk]   = *(const bf16x8*)(qs + row * 64 + g * 8);
    }
    bf16x8 sh[2][2], sl[2][2];
#pragma unroll
    for (int n = 0; n < 2; ++n)
#pragma unroll
      for (int kk = 0; kk < 2; ++kk) {
        const int vrow = n * 16 + r;
        const int g = (kk * 4 + q) ^ (vrow & 7);
        sh[n][kk] = *(const bf16x8*)(Shi + vrow * 64 + g * 8);
        sl[n][kk] = *(const bf16x8*)(Slo + vrow * 64 + g * 8);
      }
    float dl4[2][4];
#pragma unroll
    for (int n = 0; n < 2; ++n) {
      const int vloc = n * 16 + r;
      const int pg = (tb >> 3) ^ (vloc & 7);
      bf16x4 dv4 = *(const bf16x4*)(dls + vloc * 64 + pg * 8 + (tb & 7));
#pragma unroll
      for (int rr = 0; rr < 4; ++rr) dl4[n][rr] = (float)dv4[rr];
    }

    f32x4 da[2] = {}, oa[2] = {};
#pragma unroll
    for (int n = 0; n < 2; ++n)
#pragma unroll
      for (int kk = 0; kk < 2; ++kk) {
        da[n] = __builtin_amdgcn_mfma_f32_16x16x32_bf16(wahi[kk], sh[n][kk], da[n], 0, 0, 0);
        da[n] = __builtin_amdgcn_mfma_f32_16x16x32_bf16(wahi[kk], sl[n][kk], da[n], 0, 0, 0);
        da[n] = __builtin_amdgcn_mfma_f32_16x16x32_bf16(walo[kk], sh[n][kk], da[n], 0, 0, 0);
        oa[n] = __builtin_amdgcn_mfma_f32_16x16x32_bf16(qa[kk],   sh[n][kk], oa[n], 0, 0, 0);
        oa[n] = __builtin_amdgcn_mfma_f32_16x16x32_bf16(qa[kk],   sl[n][kk], oa[n], 0, 0, 0);
      }

#pragma unroll
    for (int n = 0; n < 2; ++n) {
      const int vloc = n * 16 + r;
      bf16x4 dpk, opk, fhk, flk;
#pragma unroll
      for (int rr = 0; rr < 4; ++rr) {
        float dv = dl4[n][rr] + da[n][rr];
        dpk[rr] = (bf16)dv;
        float p = fs4[rr] * dv;
        bf16 ph = (bf16)p;
        fhk[rr] = ph;
        flk[rr] = (bf16)(p - (float)ph);
        opk[rr] = (bf16)(ds4[rr] * oa[n][rr]);
      }
      *(bf16x4*)(dTg + gch + (long)vloc * 64 + tb) = dpk;
      *(bf16x4*)(o1g + gch + (long)vloc * 64 + tb) = opk;
      const int pg = (tb >> 3) ^ (vloc & 7);
      *(bf16x4*)(Dth + vloc * 64 + pg * 8 + (tb & 7)) = fhk;
      *(bf16x4*)(Dtl + vloc * 64 + pg * 8 + (tb & 7)) = flk;
    }

    // B2: LDS-only barrier; prefetch + global stores stay in flight to next B1.
    asm volatile("s_waitcnt lgkmcnt(0)" ::: "memory");
    __builtin_amdgcn_sched_barrier(0);
    __builtin_amdgcn_s_barrier();
    __builtin_amdgcn_sched_barrier(0);

    if (c < 31) {
      const float dC = dS[63];
      bf16x8 dh[2], dlo2[2], ktf[2][2];
#pragma unroll
      for (int kk = 0; kk < 2; ++kk) {
        const int vrow = va * 16 + r;
        const int g = (kk * 4 + q) ^ (vrow & 7);
        dh[kk]   = *(const bf16x8*)(Dth + vrow * 64 + g * 8);
        dlo2[kk] = *(const bf16x8*)(Dtl + vrow * 64 + g * 8);
      }
#pragma unroll
      for (int m = 0; m < 2; ++m)
#pragma unroll
        for (int kk = 0; kk < 2; ++kk) {
          const int krow = (kt0 + m) * 16 + r;
          const int g = (kk * 4 + q) ^ (krow & 7);
          ktf[m][kk] = *(const bf16x8*)(KT + krow * 64 + g * 8);
        }
#pragma unroll
      for (int m = 0; m < 2; ++m) {
        f32x4 sa;
#pragma unroll
        for (int rr = 0; rr < 4; ++rr) sa[rr] = dC * Sacc[m][rr];
#pragma unroll
        for (int kk = 0; kk < 2; ++kk) {
          sa = __builtin_amdgcn_mfma_f32_16x16x32_bf16(dh[kk],   ktf[m][kk], sa, 0, 0, 0);
          sa = __builtin_amdgcn_mfma_f32_16x16x32_bf16(dlo2[kk], ktf[m][kk], sa, 0, 0, 0);
        }
        Sacc[m] = sa;
        const int k = (kt0 + m) * 16 + r;
#pragma unroll
        for (int rr = 0; rr < 4; ++rr) {
          const int v = va * 16 + q * 4 + rr;
          float s = sa[rr];
          bf16 hh = (bf16)s;
          const int pg = (k >> 3) ^ (v & 7);
          Shi[v * 64 + pg * 8 + (k & 7)] = hh;
          Slo[v * 64 + pg * 8 + (k & 7)] = (bf16)(s - (float)hh);
        }
      }
    }
  }
}

// ---------------------------------------------------------------- phase C: outputs, MFMA
__global__ __launch_bounds__(256, 2)
void chunk_c(const bf16* __restrict__ qbuf, const bf16* __restrict__ kbuf,
             const float* __restrict__ gbuf, const bf16* __restrict__ dTg,
             const bf16* __restrict__ o1g, bf16* __restrict__ core) {
  __shared__ __align__(16) char smem[57600];
  const int t = threadIdx.x;
  const int c = blockIdx.x >> 4, h = blockIdx.x & 15;
  const long c16h = (long)(c * 16 + h);
  bf16* Qs  = (bf16*)smem;
  bf16* Ksl = (bf16*)(smem + 8192);
  bf16* Pl  = (bf16*)(smem + 16384);
  const bf16* dT  = (const bf16*)(smem + 24576);
  const bf16* o1l = (const bf16*)(smem + 40960);
  float* cumS = (float*)(smem + 57344);

#pragma unroll
  for (int it = 0; it < 2; ++it) {
    int byte = (it * 256 + t) * 16;
    int row = byte >> 7, col = (byte & 127) >> 1;
    GLDS16(qbuf + (long)(c * 64 + row) * KEY_DIM + h * DKv + col, smem + byte);
    GLDS16(kbuf + (long)(c * 64 + row) * KEY_DIM + h * DKv + col, smem + 8192 + byte);
  }
#pragma unroll
  for (int it = 0; it < 4; ++it) {
    int byte = (it * 256 + t) * 16;
    GLDS16(dTg + c16h * 8192 + (byte >> 1), smem + 24576 + byte);
    GLDS16(o1g + c16h * 8192 + (byte >> 1), smem + 40960 + byte);
  }
  if (t < 64) {
    float cc = gbuf[(long)(c * 64 + t) * NH + h];
#pragma unroll
    for (int d = 1; d < 64; d <<= 1) { float y = __shfl_up(cc, d); if (t >= d) cc += y; }
    cumS[t] = cc;
  }
  __syncthreads();

  const int lane = t & 63, wv = t >> 6;
  const int r = lane & 15, q = lane >> 4;
  const bf16x8* Qs8 = (const bf16x8*)Qs;
  const bf16x8* Ks8 = (const bf16x8*)Ksl;

#pragma unroll
  for (int n = 0; n < 4; ++n) {
    f32x4 acc = {0.f, 0.f, 0.f, 0.f};
#pragma unroll
    for (int kk = 0; kk < 2; ++kk)
      acc = __builtin_amdgcn_mfma_f32_16x16x32_bf16(
          Qs8[(wv * 16 + r) * 8 + kk * 4 + q], Ks8[(n * 16 + r) * 8 + kk * 4 + q], acc, 0, 0, 0);
    const int i = n * 16 + r;
#pragma unroll
    for (int rr = 0; rr < 4; ++rr) {
      const int tr = wv * 16 + q * 4 + rr;
      Pl[tr * 64 + i] = (i <= tr) ? (bf16)(__expf(cumS[tr] - cumS[i]) * acc[rr]) : (bf16)0.0f;
    }
  }
  __syncthreads();

  {
    const bf16x8* Pl8 = (const bf16x8*)Pl;
    const bf16x8* dT8 = (const bf16x8*)dT;
    bf16x8 pf[2];
#pragma unroll
    for (int kk = 0; kk < 2; ++kk) pf[kk] = Pl8[(wv * 16 + r) * 8 + kk * 4 + q];
#pragma unroll
    for (int n = 0; n < 8; ++n) {
      const int v = n * 16 + r;
      f32x4 acc;
#pragma unroll
      for (int rr = 0; rr < 4; ++rr)
        acc[rr] = (float)o1l[v * 64 + (wv * 16 + q * 4 + rr)];
#pragma unroll
      for (int kk = 0; kk < 2; ++kk)
        acc = __builtin_amdgcn_mfma_f32_16x16x32_bf16(
            pf[kk], dT8[(n * 16 + r) * 8 + kk * 4 + q], acc, 0, 0, 0);
#pragma unroll
      for (int rr = 0; rr < 4; ++rr) {
        const int tr = wv * 16 + q * 4 + rr;
        core[(long)(c * 64 + tr) * VAL_DIM + h * DVv + v] = (bf16)acc[rr];
      }
    }
  }
}

// ---------------------------------------------------------------- RMSNorm + SiLU(z) gate
__global__ __launch_bounds__(256)
void gate_norm(const bf16* __restrict__ core, const bf16* __restrict__ zb,
               const void* __restrict__ normwr, bf16* __restrict__ gated,
               const unsigned* __restrict__ flagp) {
  const bool f32g = (*flagp != 0);
  const int s  = blockIdx.x;
  const int t  = threadIdx.x;
  const int h  = t >> 4;
  const int li = t & 15;
  const long base = (long)s * VAL_DIM + h * DVv + li * 8;
  bf16x8 c8 = *(const bf16x8*)(core + base);
  bf16x8 z8 = *(const bf16x8*)(zb + base);
  float x[8], z[8], nw[8];
  float ss = 0.f;
#pragma unroll
  for (int j = 0; j < 8; ++j) { x[j] = (float)c8[j]; z[j] = (float)z8[j]; ss += x[j] * x[j]; }
  if (f32g) {
    const float* np_ = (const float*)normwr + li * 8;
#pragma unroll
    for (int j = 0; j < 8; ++j) nw[j] = np_[j];
  } else {
    const u16* np_ = (const u16*)normwr + li * 8;
#pragma unroll
    for (int j = 0; j < 8; ++j) nw[j] = b2f(np_[j]);
  }
  ss += __shfl_xor(ss, 1); ss += __shfl_xor(ss, 2);
  ss += __shfl_xor(ss, 4); ss += __shfl_xor(ss, 8);
  float scale = rsqrtf(ss * (1.f / 128.f) + 1e-6f);
#pragma unroll
  for (int j = 0; j < 8; ++j) {
    float y = x[j] * scale * nw[j];
    y *= z[j] * sigmoidf_(z[j]);
    gated[base + j] = (bf16)y;
  }
}

// ---------------------------------------------------------------- launcher
extern "C" void kernel_launch(void* const* d_in, const int* in_sizes, int n_in,
                              void* d_out, int out_size, void* d_ws, size_t ws_size,
                              hipStream_t stream) {
  char* ws = (char*)d_ws;
  const bool big = ws_size >= ((48u << 20) + (512u << 10));

  if (big) {
    // ws: [0,8) hsb -> vbuf -> dTg | [8,24) wcomb(qkv) -> woutb[8,16)+o1g[16,24)
    //     [24,32) wcomb(z) -> whig[24,28)+wlog[28,32) | [32,40) zbuf
    //     [40,44) qbuf [44,48) kbuf -> gated[40,48) | [48M..) eg|beta|g|flag
    // d_out: [0,16) mixed -> core[0,8)+dlocT[8,16) -> final f32 out (16M).
    bf16*  hsb   = (bf16*)ws;
    bf16*  wcomb = (bf16*)(ws + (8u << 20));    // [6144][2048] bf16 = 24 MB
    bf16*  wzpart= (bf16*)(ws + (24u << 20));   // rows 4096-6143 of wcomb
    bf16*  zbuf  = (bf16*)(ws + (32u << 20));
    bf16*  mixed = (bf16*)d_out;                // 2048x4096 bf16 = 16 MB
    bf16*  vbuf  = (bf16*)ws;                   // after gemm (hsb dead)
    bf16*  qbuf  = (bf16*)(ws + (40u << 20));
    bf16*  kbuf  = (bf16*)(ws + (44u << 20));
    bf16*  whig  = (bf16*)(ws + (24u << 20));
    bf16*  wlog  = (bf16*)(ws + (28u << 20));
    bf16*  woutb = (bf16*)(ws + (8u << 20));
    bf16*  dlocp = (bf16*)((char*)d_out + (8u << 20));
    bf16*  dTg   = (bf16*)ws;                   // after chunk_a (vbuf dead)
    bf16*  o1g   = (bf16*)(ws + (16u << 20));
    bf16*  corep = (bf16*)d_out;                // after conv (mixed dead)
    bf16*  gated = (bf16*)(ws + (40u << 20));
    float* egp  = (float*)(ws + (48u << 20));
    float* betp = (float*)(ws + (48u << 20) + (128u << 10));
    float* gbp  = (float*)(ws + (48u << 20) + (256u << 10));
    unsigned* flagp = (unsigned*)(ws + (48u << 20) + (384u << 10));

    detect_dtype<<<1, 64, 0, stream>>>((const u16*)d_in[0], flagp);
    proj_ab<<<SEQ / 4, 256, 0, stream>>>(d_in[0], d_in[2], d_in[3], d_in[6], d_in[7], egp, betp, gbp, flagp);
    cvt_bf16<<<(SEQ * HIDDEN) / 2048, 256, 0, stream>>>(d_in[0], hsb, (long)SEQ * HIDDEN, flagp);
    cvt_bf16<<<(CONV_DIM * HIDDEN) / 2048, 256, 0, stream>>>(d_in[1], wcomb, (long)CONV_DIM * HIDDEN, flagp);
    cvt_bf16<<<(VAL_DIM * HIDDEN) / 2048, 256, 0, stream>>>(d_in[4], wzpart, (long)VAL_DIM * HIDDEN, flagp);
    gemm_qkvz<<<dim3((CONV_DIM + VAL_DIM) / 128, SEQ / 128), 256, 0, stream>>>(hsb, wcomb, mixed, zbuf);
    conv_norm<<<dim3(SEQ, CONV_DIM / 256), 256, 0, stream>>>(mixed, d_in[5], qbuf, kbuf, vbuf, flagp);
    chunk_a<<<512 + 2048, 256, 0, stream>>>(kbuf, vbuf, gbp, betp, dlocp, whig, wlog,
                                            d_in[9], woutb, flagp);
    chunk_b<<<64, 256, 0, stream>>>(qbuf, kbuf, gbp, dlocp, whig, wlog, dTg, o1g);
    chunk_c<<<512, 256, 0, stream>>>(qbuf, kbuf, gbp, dTg, o1g, corep);
    gate_norm<<<SEQ, 256, 0, stream>>>(corep, zbuf, d_in[8], gated, flagp);
    gemm_nt<true><<<dim3(HIDDEN / 128, SEQ / 128), 256, 0, stream>>>(gated, woutb, d_out, HIDDEN, VAL_DIM, flagp, 0, 0);
  } else {
    // Fallback layout (peak 24.26 MiB): r6-style staging GEMMs; per-step scan.
    bf16* mixed = (bf16*)ws;
    bf16* qbuf  = (bf16*)(ws + (16u << 20));
    bf16* kbuf  = (bf16*)(ws + (20u << 20));
    bf16* zbuf  = (bf16*)ws;
    bf16* corep = (bf16*)(ws + (8u << 20));
    bf16* gated = (bf16*)(ws + (16u << 20));
    float* egp  = (float*)(ws + (24u << 20));
    float* betp = (float*)(ws + (24u << 20) + (128u << 10));
    unsigned* flagp = (unsigned*)(ws + (24u << 20) + (256u << 10));
    bf16* vbuf  = (bf16*)d_out;

    detect_dtype<<<1, 64, 0, stream>>>((const u16*)d_in[0], flagp);
    proj_ab<<<SEQ / 4, 256, 0, stream>>>(d_in[0], d_in[2], d_in[3], d_in[6], d_in[7], egp, betp, nullptr, flagp);
    gemm_nt<false><<<dim3(CONV_DIM / 128, SEQ / 128), 256, 0, stream>>>(d_in[0], d_in[1], mixed, CONV_DIM, HIDDEN, flagp, 1, 1);
    conv_norm<<<dim3(SEQ, CONV_DIM / 256), 256, 0, stream>>>(mixed, d_in[5], qbuf, kbuf, vbuf, flagp);
    gemm_nt<false><<<dim3(VAL_DIM / 128, SEQ / 128), 256, 0, stream>>>(d_in[0], d_in[4], zbuf, VAL_DIM, HIDDEN, flagp, 1, 1);
    fused_scan<<<128, 256, 0, stream>>>(qbuf, kbuf, vbuf, egp, betp, corep,
                                        nullptr, nullptr, nullptr, nullptr, nullptr, flagp,
                                        128, 0);
    gate_norm<<<SEQ, 256, 0, stream>>>(corep, zbuf, d_in[8], gated, flagp);
    gemm_nt<true><<<dim3(HIDDEN / 128, SEQ / 128), 256, 0, stream>>>(gated, d_in[9], d_out, HIDDEN, VAL_DIM, flagp, 0, 1);
  }
}